// Round 1
// baseline (9789.771 us; speedup 1.0000x reference)
//
#include <hip/hip_runtime.h>
#include <math.h>

#define B_ 8
#define C_ 256
#define NPIX 4096      // 64*64
#define NP 1024        // 32*32

// ---------- reductions ----------
__device__ __forceinline__ float wave_reduce_sum(float v) {
#pragma unroll
  for (int off = 32; off > 0; off >>= 1) v += __shfl_down(v, off, 64);
  return v;
}
__device__ __forceinline__ float wave_reduce_max(float v) {
#pragma unroll
  for (int off = 32; off > 0; off >>= 1) v = fmaxf(v, __shfl_down(v, off, 64));
  return v;
}

// ---------- bilinear resize, align_corners=True, bit-exact f32 linspace ----------
__global__ __launch_bounds__(256) void k_resize(const float* __restrict__ in, float* __restrict__ out,
                                                int IH, int IW, int OH, int OW, int nElem) {
  int idx = blockIdx.x * 256 + threadIdx.x;
  if (idx >= nElem) return;
  int ox = idx % OW; int t = idx / OW; int oy = t % OH; int bc = t / OH;
  float dy = (float)(IH - 1) / (float)(OH - 1);
  float dx = (float)(IW - 1) / (float)(OW - 1);
  float yf = (float)oy * dy;
  float xf = (float)ox * dx;
  float y0f = floorf(yf), x0f = floorf(xf);
  int y0 = (int)y0f, x0 = (int)x0f;
  int y1 = min(y0 + 1, IH - 1), x1 = min(x0 + 1, IW - 1);
  float wy = yf - y0f, wx = xf - x0f;
  const float* p = in + (size_t)bc * IH * IW;
  float a = p[y0 * IW + x0], b = p[y0 * IW + x1];
  float c = p[y1 * IW + x0], d = p[y1 * IW + x1];
  float top = a * (1.0f - wx) + b * wx;
  float bot = c * (1.0f - wx) + d * wx;
  out[idx] = top * (1.0f - wy) + bot * wy;
}

// ---------- Sum = fg + bg ----------
__global__ __launch_bounds__(256) void k_sum(const float4* __restrict__ a, const float4* __restrict__ b,
                                             float4* __restrict__ o, int n4) {
  int i = blockIdx.x * 256 + threadIdx.x;
  int stride = gridDim.x * 256;
  for (; i < n4; i += stride) {
    float4 x = a[i], y = b[i];
    o[i] = make_float4(x.x + y.x, x.y + y.y, x.z + y.z, x.w + y.w);
  }
}

// ---------- conv1: t = Wc*(Sum*(1-m)) + Wm*(Sum*m) + bc + bm ----------
__global__ __launch_bounds__(256) void k_conv1(const float* __restrict__ Sum, const float* __restrict__ m64,
                                               const float* __restrict__ Wc, const float* __restrict__ bc,
                                               const float* __restrict__ Wm, const float* __restrict__ bm,
                                               float* __restrict__ tout) {
  int st = blockIdx.x, cog = blockIdx.y, b = blockIdx.z;
  int ty0 = (st >> 2) * 16, tx0 = (st & 3) * 16;
  int tid = threadIdx.x, tx = tid & 15, ty = tid >> 4;
  __shared__ float sS[324];   // 18x18 input tile
  __shared__ float sM[324];   // 18x18 mask tile
  __shared__ float sW[384];   // [2][16co][12(9 used)]
  for (int i = tid; i < 324; i += 256) {
    int r = i / 18, c = i % 18;
    int gy = ty0 + r - 1, gx = tx0 + c - 1;
    float v = 0.f;
    if (gy >= 0 && gy < 64 && gx >= 0 && gx < 64) v = m64[b * NPIX + gy * 64 + gx];
    sM[i] = v;
  }
  __syncthreads();
  float mw[9];
#pragma unroll
  for (int k = 0; k < 3; k++)
#pragma unroll
    for (int l = 0; l < 3; l++) mw[k * 3 + l] = sM[(ty + k) * 18 + tx + l];
  float acc[16];
#pragma unroll
  for (int i = 0; i < 16; i++) acc[i] = 0.f;
  const float* Wcb = Wc + (size_t)(cog * 16) * 2304;
  const float* Wmb = Wm + (size_t)(cog * 16) * 2304;
  for (int ci = 0; ci < 256; ci++) {
    __syncthreads();
    for (int i = tid; i < 324; i += 256) {
      int r = i / 18, c = i % 18;
      int gy = ty0 + r - 1, gx = tx0 + c - 1;
      float v = 0.f;
      if (gy >= 0 && gy < 64 && gx >= 0 && gx < 64) v = Sum[((size_t)(b * 256 + ci) * 64 + gy) * 64 + gx];
      sS[i] = v;
    }
    for (int i = tid; i < 288; i += 256) {
      int half = i / 144, r = i % 144, co = r / 9, k = r % 9;
      sW[half * 192 + co * 12 + k] = (half ? Wmb : Wcb)[(size_t)co * 2304 + ci * 9 + k];
    }
    __syncthreads();
    float a[9], c2[9];
#pragma unroll
    for (int k = 0; k < 3; k++)
#pragma unroll
      for (int l = 0; l < 3; l++) {
        float s = sS[(ty + k) * 18 + tx + l];
        float m = mw[k * 3 + l];
        a[k * 3 + l] = s * (1.0f - m);
        c2[k * 3 + l] = s * m;
      }
#pragma unroll
    for (int co = 0; co < 16; co++) {
      float t0 = 0.f;
#pragma unroll
      for (int j = 0; j < 9; j++) t0 += a[j] * sW[co * 12 + j] + c2[j] * sW[192 + co * 12 + j];
      acc[co] += t0;
    }
  }
  int gy = ty0 + ty, gx = tx0 + tx;
#pragma unroll
  for (int co = 0; co < 16; co++) {
    int coG = cog * 16 + co;
    tout[((size_t)(b * 256 + coG) * 64 + gy) * 64 + gx] = acc[co] + bc[coG] + bm[coG];
  }
}

// ---------- conv2: x = Wf * t + bf ----------
__global__ __launch_bounds__(256) void k_conv2(const float* __restrict__ tin, const float* __restrict__ Wf,
                                               const float* __restrict__ bf, float* __restrict__ xout) {
  int st = blockIdx.x, cog = blockIdx.y, b = blockIdx.z;
  int ty0 = (st >> 2) * 16, tx0 = (st & 3) * 16;
  int tid = threadIdx.x, tx = tid & 15, ty = tid >> 4;
  __shared__ float sS[324];
  __shared__ float sW[192];
  float acc[16];
#pragma unroll
  for (int i = 0; i < 16; i++) acc[i] = 0.f;
  const float* Wb = Wf + (size_t)(cog * 16) * 2304;
  for (int ci = 0; ci < 256; ci++) {
    __syncthreads();
    for (int i = tid; i < 324; i += 256) {
      int r = i / 18, c = i % 18;
      int gy = ty0 + r - 1, gx = tx0 + c - 1;
      float v = 0.f;
      if (gy >= 0 && gy < 64 && gx >= 0 && gx < 64) v = tin[((size_t)(b * 256 + ci) * 64 + gy) * 64 + gx];
      sS[i] = v;
    }
    if (tid < 144) {
      int co = tid / 9, k = tid % 9;
      sW[co * 12 + k] = Wb[(size_t)co * 2304 + ci * 9 + k];
    }
    __syncthreads();
    float a[9];
#pragma unroll
    for (int k = 0; k < 3; k++)
#pragma unroll
      for (int l = 0; l < 3; l++) a[k * 3 + l] = sS[(ty + k) * 18 + tx + l];
#pragma unroll
    for (int co = 0; co < 16; co++) {
      float t0 = 0.f;
#pragma unroll
      for (int j = 0; j < 9; j++) t0 += a[j] * sW[co * 12 + j];
      acc[co] += t0;
    }
  }
  int gy = ty0 + ty, gx = tx0 + tx;
#pragma unroll
  for (int co = 0; co < 16; co++) {
    int coG = cog * 16 + co;
    xout[((size_t)(b * 256 + coG) * 64 + gy) * 64 + gx] = acc[co] + bf[coG];
  }
}

// ---------- instance norm + swish, in place, one block per (b,c) ----------
__global__ __launch_bounds__(256) void k_innorm(float* __restrict__ x) {
  __shared__ float s4[4];
  int bc = blockIdx.x;
  float* p = x + (size_t)bc * NPIX;
  int tid = threadIdx.x;
  int lane = tid & 63, w = tid >> 6;
  float v[16];
  float s = 0.f;
#pragma unroll
  for (int i = 0; i < 16; i++) { v[i] = p[tid + i * 256]; s += v[i]; }
  s = wave_reduce_sum(s);
  if (lane == 0) s4[w] = s;
  __syncthreads();
  float mean = (s4[0] + s4[1] + s4[2] + s4[3]) * (1.0f / 4096.0f);
  __syncthreads();
  float s2 = 0.f;
#pragma unroll
  for (int i = 0; i < 16; i++) { float d = v[i] - mean; s2 += d * d; }
  s2 = wave_reduce_sum(s2);
  if (lane == 0) s4[w] = s2;
  __syncthreads();
  float var = (s4[0] + s4[1] + s4[2] + s4[3]) * (1.0f / 4096.0f);
  float inv = 1.0f / sqrtf(var + 1e-5f);
#pragma unroll
  for (int i = 0; i < 16; i++) {
    float xn = (v[i] - mean) * inv;
    float sg = 1.0f / (1.0f + expf(-xn));
    p[tid + i * 256] = xn * sg;
  }
}

// ---------- per-pixel channel sum of squares of x_down ----------
__global__ __launch_bounds__(256) void k_sq32(const float* __restrict__ xd, float* __restrict__ sq) {
  int idx = blockIdx.x * 256 + threadIdx.x;
  if (idx >= B_ * NP) return;
  int pix = idx & 1023; int b = idx >> 10;
  const float* p = xd + (size_t)b * C_ * NP + pix;
  float s = 0.f;
  for (int c = 0; c < C_; c++) { float v = p[c * NP]; s += v * v; }
  sq[idx] = s;
}

// ---------- fq[q] = mm ? 1/max(norm,1e-4) : 0 ----------
__global__ __launch_bounds__(256) void k_normmm(const float* __restrict__ sq, const float* __restrict__ m32,
                                                float* __restrict__ fq) {
  int idx = blockIdx.x * 256 + threadIdx.x;
  if (idx >= B_ * NP) return;
  int q = idx & 1023, b = idx >> 10;
  int qi = q >> 5, qj = q & 31;
  float ns = 0.f, ms = 0.f;
#pragma unroll
  for (int k = 0; k < 3; k++)
#pragma unroll
    for (int l = 0; l < 3; l++) {
      int r = qi + k - 1, c = qj + l - 1;
      if (r >= 0 && r < 32 && c >= 0 && c < 32) {
        ns += sq[b * NP + r * 32 + c];
        ms += m32[b * NP + r * 32 + c];
      }
    }
  float f = (ms == 0.0f) ? (1.0f / fmaxf(sqrtf(ns), 1e-4f)) : 0.0f;
  fq[idx] = f;
}

// ---------- Gram: sc[b,p,q] = (pt_p . pt_q) * fq[q]  (implicit im2col) ----------
__global__ __launch_bounds__(256) void k_gram(const float* __restrict__ xd, const float* __restrict__ fq,
                                              float* __restrict__ sc) {
  int bp = blockIdx.x, bq = blockIdx.y, b = blockIdx.z;
  int pi0 = bp * 2, qi0 = bq * 2;
  __shared__ float sA[544], sB[544];   // [c4][4 rows][34 cols]
  int tid = threadIdx.x;
  int tq = tid & 15, tp = tid >> 4;
  int p4 = tp * 4, q4 = tq * 4;
  int pil = p4 >> 5, pj0 = p4 & 31;
  int qil = q4 >> 5, qj0 = q4 & 31;
  float acc[4][4];
#pragma unroll
  for (int i = 0; i < 4; i++)
#pragma unroll
    for (int j = 0; j < 4; j++) acc[i][j] = 0.f;
  const float* xb = xd + (size_t)b * C_ * NP;
  for (int c0 = 0; c0 < 256; c0 += 4) {
    __syncthreads();
    for (int i = tid; i < 1088; i += 256) {
      int which = i >= 544;
      int j = which ? i - 544 : i;
      int cc = j / 136, rem = j % 136;
      int r = rem / 34, col = rem % 34;
      int gy = (which ? qi0 : pi0) + r - 1;
      int gx = col - 1;
      float v = 0.f;
      if (gy >= 0 && gy < 32 && gx >= 0 && gx < 32) v = xb[(size_t)(c0 + cc) * NP + gy * 32 + gx];
      float* dst = which ? sB : sA;
      dst[j] = v;
    }
    __syncthreads();
#pragma unroll
    for (int cc = 0; cc < 4; cc++) {
#pragma unroll
      for (int k = 0; k < 3; k++) {
        float ra[6], rb[6];
#pragma unroll
        for (int u = 0; u < 6; u++) ra[u] = sA[cc * 136 + (pil + k) * 34 + pj0 + u];
#pragma unroll
        for (int u = 0; u < 6; u++) rb[u] = sB[cc * 136 + (qil + k) * 34 + qj0 + u];
#pragma unroll
        for (int l = 0; l < 3; l++)
#pragma unroll
          for (int i2 = 0; i2 < 4; i2++)
#pragma unroll
            for (int j2 = 0; j2 < 4; j2++) acc[i2][j2] += ra[i2 + l] * rb[j2 + l];
      }
    }
  }
  int p0 = bp * 64 + p4, q0 = bq * 64 + q4;
#pragma unroll
  for (int i2 = 0; i2 < 4; i2++)
#pragma unroll
    for (int j2 = 0; j2 < 4; j2++) {
      int q = q0 + j2;
      sc[((size_t)b * NP + (p0 + i2)) * NP + q] = acc[i2][j2] * fq[b * NP + q];
    }
}

// ---------- softmax over q (axis=1) for each (b,p); att = softmax(10*s)*mm, clip 1e-8 ----------
__global__ __launch_bounds__(256) void k_softmax(float* __restrict__ sc, const float* __restrict__ fq) {
  __shared__ float s4[4];
  int row = blockIdx.x;        // b*1024 + p
  int b = row >> 10;
  float* r = sc + (size_t)row * NP;
  int tid = threadIdx.x;
  int lane = tid & 63, w = tid >> 6;
  float4 sv = *(const float4*)&r[tid * 4];
  float l0 = sv.x * 10.f, l1 = sv.y * 10.f, l2 = sv.z * 10.f, l3 = sv.w * 10.f;
  float mx = fmaxf(fmaxf(l0, l1), fmaxf(l2, l3));
  mx = wave_reduce_max(mx);
  if (lane == 0) s4[w] = mx;
  __syncthreads();
  float M = fmaxf(fmaxf(s4[0], s4[1]), fmaxf(s4[2], s4[3]));
  __syncthreads();
  float e0 = expf(l0 - M), e1 = expf(l1 - M), e2 = expf(l2 - M), e3 = expf(l3 - M);
  float s = e0 + e1 + e2 + e3;
  s = wave_reduce_sum(s);
  if (lane == 0) s4[w] = s;
  __syncthreads();
  float inv = 1.0f / (s4[0] + s4[1] + s4[2] + s4[3]);
  const float* fb = fq + b * NP + tid * 4;
  float m0 = fb[0] > 0.f ? 1.f : 0.f;
  float m1 = fb[1] > 0.f ? 1.f : 0.f;
  float m2 = fb[2] > 0.f ? 1.f : 0.f;
  float m3 = fb[3] > 0.f ? 1.f : 0.f;
  float a0 = fmaxf(e0 * inv * m0, 1e-8f);
  float a1 = fmaxf(e1 * inv * m1, 1e-8f);
  float a2 = fmaxf(e2 * inv * m2, 1e-8f);
  float a3 = fmaxf(e3 * inv * m3, 1e-8f);
  *(float4*)&r[tid * 4] = make_float4(a0, a1, a2, a3);
}

// ---------- out = x*(1-m64) ----------
__global__ __launch_bounds__(256) void k_initout(const float4* __restrict__ x, const float* __restrict__ m64,
                                                 float4* __restrict__ out) {
  int i = blockIdx.x * 256 + threadIdx.x;
  if (i >= (B_ * C_ * NPIX) / 4) return;
  int e = i * 4;
  int pix = e & (NPIX - 1);
  int b = e / (C_ * NPIX);
  const float4 mv = *(const float4*)&m64[b * NPIX + pix];
  float4 xv = x[i];
  out[i] = make_float4(xv.x * (1.f - mv.x), xv.y * (1.f - mv.y), xv.z * (1.f - mv.z), xv.w * (1.f - mv.w));
}

// ---------- F-GEMM + scatter: out += 0.25*m64 * sum_q att[p,q]*x_pad[co,2qi+ky-1,2qj+kx-1] ----------
__global__ __launch_bounds__(256) void k_fgemm(const float* __restrict__ att, const float* __restrict__ x,
                                               const float* __restrict__ m64, float* __restrict__ out) {
  int pt = blockIdx.x;
  int kk = blockIdx.y; int ky = kk >> 2, kx = kk & 3;
  int b = blockIdx.z;
  int tid = threadIdx.x;
  __shared__ float sA[1024];       // [p64][q16]
  __shared__ float sB[16 * 260];   // [q16][co256 pad 260]
  float acc[4][16];
#pragma unroll
  for (int i = 0; i < 4; i++)
#pragma unroll
    for (int j = 0; j < 16; j++) acc[i][j] = 0.f;
  const float* ab = att + ((size_t)b * NP + pt * 64) * NP;
  const float* xb = x + (size_t)b * C_ * NPIX;
  int tco = tid & 15, tpp = tid >> 4;
  for (int q0 = 0; q0 < 1024; q0 += 16) {
    __syncthreads();
    {
      int p = tid >> 2, qo = (tid & 3) * 4;
      float4 v = *(const float4*)(ab + (size_t)p * NP + q0 + qo);
      *(float4*)&sA[p * 16 + qo] = v;
    }
    {
      int qv = tid & 15, cob = tid >> 4;
      int q = q0 + qv; int qi = q >> 5, qj = q & 31;
      int gy = 2 * qi + ky - 1, gx = 2 * qj + kx - 1;
      bool inb = (gy >= 0 && gy < 64 && gx >= 0 && gx < 64);
      const float* xp = xb + gy * 64 + gx;
#pragma unroll
      for (int it = 0; it < 16; it++) {
        int co = cob + it * 16;
        sB[qv * 260 + co] = inb ? xp[(size_t)co * NPIX] : 0.f;
      }
    }
    __syncthreads();
#pragma unroll 4
    for (int qq = 0; qq < 16; qq++) {
      float a0 = sA[(tpp * 4 + 0) * 16 + qq];
      float a1 = sA[(tpp * 4 + 1) * 16 + qq];
      float a2 = sA[(tpp * 4 + 2) * 16 + qq];
      float a3 = sA[(tpp * 4 + 3) * 16 + qq];
#pragma unroll
      for (int j = 0; j < 16; j++) {
        float bv = sB[qq * 260 + tco + j * 16];
        acc[0][j] += a0 * bv;
        acc[1][j] += a1 * bv;
        acc[2][j] += a2 * bv;
        acc[3][j] += a3 * bv;
      }
    }
  }
#pragma unroll
  for (int i = 0; i < 4; i++) {
    int ploc = tpp * 4 + i;
    int p = pt * 64 + ploc;
    int pi = p >> 5, pj = p & 31;
    int oy = 2 * pi + ky - 1, ox = 2 * pj + kx - 1;
    if (oy < 0 || oy >= 64 || ox < 0 || ox >= 64) continue;
    float msc = 0.25f * m64[b * NPIX + oy * 64 + ox];
    if (msc == 0.0f) continue;
    float* ob = out + ((size_t)b * C_ + tco) * NPIX + oy * 64 + ox;
#pragma unroll
    for (int j = 0; j < 16; j++) {
      atomicAdd(ob + (size_t)j * 16 * NPIX, acc[i][j] * msc);
    }
  }
}

extern "C" void kernel_launch(void* const* d_in, const int* in_sizes, int n_in,
                              void* d_out, int out_size, void* d_ws, size_t ws_size,
                              hipStream_t stream) {
  const float* bg   = (const float*)d_in[0];
  const float* fg   = (const float*)d_in[1];
  const float* mask = (const float*)d_in[2];
  const float* Wc   = (const float*)d_in[3];
  const float* bc   = (const float*)d_in[4];
  const float* Wm   = (const float*)d_in[5];
  const float* bm   = (const float*)d_in[6];
  const float* Wf   = (const float*)d_in[7];
  const float* bf   = (const float*)d_in[8];
  float* out = (float*)d_out;
  float* w = (float*)d_ws;

  float* mask64 = w;                 // 32768
  float* mask32 = w + 32768;         // 8192
  float* sq32   = w + 40960;         // 8192
  float* fq     = w + 49152;         // 8192
  float* SumAtt = w + 57344;         // 8388608  (Sum; later score/att, aliased)
  float* tbuf   = w + 8445952;       // 8388608
  float* xbuf   = w + 16834560;      // 8388608
  float* xd     = w + 25223168;      // 2097152   total 27,320,320 floats = 109.3 MB

  // mask 256 -> 64
  hipLaunchKernelGGL(k_resize, dim3(128), dim3(256), 0, stream, mask, mask64, 256, 256, 64, 64, 32768);
  // Sum = fg + bg
  hipLaunchKernelGGL(k_sum, dim3(4096), dim3(256), 0, stream, (const float4*)fg, (const float4*)bg,
                     (float4*)SumAtt, (B_ * C_ * NPIX) / 4);
  // conv1 (dual) -> tbuf
  hipLaunchKernelGGL(k_conv1, dim3(16, 16, 8), dim3(256), 0, stream, SumAtt, mask64, Wc, bc, Wm, bm, tbuf);
  // conv2 -> xbuf (raw)
  hipLaunchKernelGGL(k_conv2, dim3(16, 16, 8), dim3(256), 0, stream, tbuf, Wf, bf, xbuf);
  // instance norm + swish in place
  hipLaunchKernelGGL(k_innorm, dim3(B_ * C_), dim3(256), 0, stream, xbuf);
  // x -> x_down (64 -> 32)
  hipLaunchKernelGGL(k_resize, dim3(8192), dim3(256), 0, stream, xbuf, xd, 64, 64, 32, 32, B_ * C_ * NP);
  // mask64 -> mask32
  hipLaunchKernelGGL(k_resize, dim3(32), dim3(256), 0, stream, mask64, mask32, 64, 64, 32, 32, B_ * NP);
  // per-pixel channel sumsq of x_down
  hipLaunchKernelGGL(k_sq32, dim3(32), dim3(256), 0, stream, xd, sq32);
  // fq = mm / max(norm,1e-4)
  hipLaunchKernelGGL(k_normmm, dim3(32), dim3(256), 0, stream, sq32, mask32, fq);
  // Gram -> score_t[b,p,q] (into SumAtt, Sum is dead now)
  hipLaunchKernelGGL(k_gram, dim3(16, 16, 8), dim3(256), 0, stream, xd, fq, SumAtt);
  // softmax over q, in place -> att_t[b,p,q]
  hipLaunchKernelGGL(k_softmax, dim3(B_ * NP), dim3(256), 0, stream, SumAtt, fq);
  // out = x*(1-m)
  hipLaunchKernelGGL(k_initout, dim3(8192), dim3(256), 0, stream, (const float4*)xbuf, mask64, (float4*)out);
  // F-GEMM + scatter: out += 0.25*m*conv_transpose(att, raw_w)
  hipLaunchKernelGGL(k_fgemm, dim3(16, 16, 8), dim3(256), 0, stream, SumAtt, xbuf, mask64, out);
}

// Round 2
// 2419.432 us; speedup vs baseline: 4.0463x; 4.0463x over previous
//
#include <hip/hip_runtime.h>
#include <math.h>

#define B_ 8
#define C_ 256
#define NPIX 4096      // 64*64
#define NP 1024        // 32*32

typedef __attribute__((ext_vector_type(8))) short bf16x8;
typedef __attribute__((ext_vector_type(4))) float f32x4;

__device__ __forceinline__ unsigned short f2bf(float f) {
  unsigned int u = __float_as_uint(f);
  unsigned int r = (u + 0x7FFFu + ((u >> 16) & 1u)) >> 16;
  return (unsigned short)r;
}
__device__ __forceinline__ unsigned int pk2(unsigned short lo, unsigned short hi) {
  return (unsigned int)lo | ((unsigned int)hi << 16);
}

// ---------- reductions ----------
__device__ __forceinline__ float wave_reduce_sum(float v) {
#pragma unroll
  for (int off = 32; off > 0; off >>= 1) v += __shfl_down(v, off, 64);
  return v;
}
__device__ __forceinline__ float wave_reduce_max(float v) {
#pragma unroll
  for (int off = 32; off > 0; off >>= 1) v = fmaxf(v, __shfl_down(v, off, 64));
  return v;
}

// ---------- bilinear resize, align_corners=True, bit-exact f32 linspace ----------
__global__ __launch_bounds__(256) void k_resize(const float* __restrict__ in, float* __restrict__ out,
                                                int IH, int IW, int OH, int OW, int nElem) {
  int idx = blockIdx.x * 256 + threadIdx.x;
  if (idx >= nElem) return;
  int ox = idx % OW; int t = idx / OW; int oy = t % OH; int bc = t / OH;
  float dy = (float)(IH - 1) / (float)(OH - 1);
  float dx = (float)(IW - 1) / (float)(OW - 1);
  float yf = (float)oy * dy;
  float xf = (float)ox * dx;
  float y0f = floorf(yf), x0f = floorf(xf);
  int y0 = (int)y0f, x0 = (int)x0f;
  int y1 = min(y0 + 1, IH - 1), x1 = min(x0 + 1, IW - 1);
  float wy = yf - y0f, wx = xf - x0f;
  const float* p = in + (size_t)bc * IH * IW;
  float a = p[y0 * IW + x0], b = p[y0 * IW + x1];
  float c = p[y1 * IW + x0], d = p[y1 * IW + x1];
  float top = a * (1.0f - wx) + b * wx;
  float bot = c * (1.0f - wx) + d * wx;
  out[idx] = top * (1.0f - wy) + bot * wy;
}

// ---------- weight prep: Wc,Wm -> Wp1[kk 0..17][co][ci] bf16; Wf -> Wp2[kk 0..8][co][ci] ----------
__global__ __launch_bounds__(256) void k_wprep(const float* __restrict__ Wc, const float* __restrict__ Wm,
                                               const float* __restrict__ Wf,
                                               unsigned short* __restrict__ Wp1, unsigned short* __restrict__ Wp2) {
  int idx = blockIdx.x * 256 + threadIdx.x;
  if (idx >= 3 * 589824) return;
  int part = idx / 589824;            // 0=Wc 1=Wm 2=Wf
  int rem = idx % 589824;             // kk*65536 + co*256 + ci
  int kk = rem >> 16, co = (rem >> 8) & 255, ci = rem & 255;
  const float* W = (part == 0) ? Wc : (part == 1) ? Wm : Wf;
  unsigned short o = f2bf(W[(size_t)co * 2304 + ci * 9 + kk]);
  if (part == 0) Wp1[rem] = o;
  else if (part == 1) Wp1[589824 + rem] = o;
  else Wp2[rem] = o;
}

__global__ __launch_bounds__(256) void k_bias(const float* __restrict__ bc, const float* __restrict__ bm,
                                              float* __restrict__ bias1) {
  int i = threadIdx.x;
  bias1[i] = bc[i] + bm[i];
}

// ---------- A prep: A0 = bf16((fg+bg)*(1-m)), A1 = bf16((fg+bg)*m), layout [b][ci][pix] ----------
__global__ __launch_bounds__(256) void k_prepA(const float* __restrict__ fg, const float* __restrict__ bg,
                                               const float* __restrict__ m64,
                                               unsigned short* __restrict__ A0, unsigned short* __restrict__ A1) {
  int i = blockIdx.x * 256 + threadIdx.x;
  if (i >= (B_ * C_ * NPIX) / 4) return;
  int e = i * 4;
  int pix = e & (NPIX - 1);
  int b = e >> 20;                      // 256*4096 = 2^20
  float4 f = ((const float4*)fg)[i];
  float4 g = ((const float4*)bg)[i];
  float4 m = *(const float4*)&m64[(b << 12) + pix];
  float s0 = f.x + g.x, s1 = f.y + g.y, s2 = f.z + g.z, s3 = f.w + g.w;
  uint2 a0, a1;
  a0.x = pk2(f2bf(s0 * (1.f - m.x)), f2bf(s1 * (1.f - m.y)));
  a0.y = pk2(f2bf(s2 * (1.f - m.z)), f2bf(s3 * (1.f - m.w)));
  a1.x = pk2(f2bf(s0 * m.x), f2bf(s1 * m.y));
  a1.y = pk2(f2bf(s2 * m.z), f2bf(s3 * m.w));
  ((uint2*)A0)[i] = a0;
  ((uint2*)A1)[i] = a1;
}

// ---------- MFMA implicit-GEMM conv: out[b][co][pix] = sum_kk sum_ci W[kk][co][ci]*A_kk[ci][pix] + bias ----------
// Block tile: 128 pix x 128 co, 4 waves (2x2), wave tile 64x64 (4x4 MFMA frags), K-chunk 32.
__device__ __forceinline__ int swz(int row, int slot) {
  return row * 32 + ((slot ^ (row & 3) ^ ((row >> 2) & 3)) << 3);   // ushort units
}

template <int NKK, bool OUT_BF16>
__global__ __launch_bounds__(256) void k_conv_mfma(const unsigned short* __restrict__ A0,
                                                   const unsigned short* __restrict__ A1,
                                                   const unsigned short* __restrict__ Wp,
                                                   const float* __restrict__ bias,
                                                   void* __restrict__ outp) {
  __shared__ __align__(16) unsigned short Alds[4096];   // [128 pix][32 ci] swizzled
  __shared__ __align__(16) unsigned short Blds[4096];   // [128 co ][32 ci] swizzled
  int bp = blockIdx.x, cot = blockIdx.y, b = blockIdx.z;
  int tid = threadIdx.x;
  int lane = tid & 63, wave = tid >> 6;
  int wm = wave >> 1, wn = wave & 1;
  f32x4 acc[4][4];
#pragma unroll
  for (int i = 0; i < 4; i++)
#pragma unroll
    for (int j = 0; j < 4; j++) acc[i][j] = (f32x4){0.f, 0.f, 0.f, 0.f};

  int sp = tid & 127;      // A: pixel-in-tile; B: co-in-tile
  int hg = tid >> 7;       // ci half (16 each)
  int pr = sp >> 6, pc = sp & 63;
  int y0 = bp * 2;

  for (int kk = 0; kk < NKK; ++kk) {
    int kw = (kk < 9) ? kk : kk - 9;
    int ky = kw / 3, kx = kw % 3;
    const unsigned short* Asrc = (NKK == 18 && kk >= 9) ? A1 : A0;
    int gy = y0 + pr + ky - 1, gx = pc + kx - 1;
    bool valid = (gy >= 0 && gy < 64 && gx >= 0 && gx < 64);
    const unsigned short* abase = Asrc + ((size_t)b * C_ * NPIX + gy * 64 + gx);
    const unsigned short* wbase = Wp + ((size_t)(kk * 256 + cot * 128 + sp) * 256 + hg * 16);

    for (int ci0 = 0; ci0 < 256; ci0 += 32) {
      __syncthreads();   // previous chunk's reads complete
      // --- stage A: this thread covers pixel sp, ci [ci0+hg*16, +16) ---
      unsigned short av[16];
#pragma unroll
      for (int j = 0; j < 16; j++) {
        int ci = ci0 + hg * 16 + j;
        av[j] = valid ? abase[(size_t)ci * NPIX] : (unsigned short)0;
      }
      {
        uint4 w0 = {pk2(av[0], av[1]), pk2(av[2], av[3]), pk2(av[4], av[5]), pk2(av[6], av[7])};
        uint4 w1 = {pk2(av[8], av[9]), pk2(av[10], av[11]), pk2(av[12], av[13]), pk2(av[14], av[15])};
        *(uint4*)&Alds[swz(sp, hg * 2 + 0)] = w0;
        *(uint4*)&Alds[swz(sp, hg * 2 + 1)] = w1;
      }
      // --- stage B: co row sp, ci [ci0+hg*16, +16) (already bf16, contiguous) ---
      {
        uint4 b0 = *(const uint4*)(wbase + ci0);
        uint4 b1 = *(const uint4*)(wbase + ci0 + 8);
        *(uint4*)&Blds[swz(sp, hg * 2 + 0)] = b0;
        *(uint4*)&Blds[swz(sp, hg * 2 + 1)] = b1;
      }
      __syncthreads();
      // --- fragments + MFMA ---
      int slot = lane >> 4;
      int mr = wm * 64 + (lane & 15);
      int nc = wn * 64 + (lane & 15);
      bf16x8 af[4], bfr[4];
#pragma unroll
      for (int i = 0; i < 4; i++) af[i] = *(const bf16x8*)&Alds[swz(mr + i * 16, slot)];
#pragma unroll
      for (int j = 0; j < 4; j++) bfr[j] = *(const bf16x8*)&Blds[swz(nc + j * 16, slot)];
#pragma unroll
      for (int i = 0; i < 4; i++)
#pragma unroll
        for (int j = 0; j < 4; j++)
          acc[i][j] = __builtin_amdgcn_mfma_f32_16x16x32_bf16(af[i], bfr[j], acc[i][j], 0, 0, 0);
    }
  }
  // epilogue: D[m][n]: n(co) = lane&15 + j*16, m(pix) = (lane>>4)*4 + r + i*16
  int co0 = cot * 128 + wn * 64 + (lane & 15);
  int px0 = bp * 128 + wm * 64 + ((lane >> 4) << 2);
#pragma unroll
  for (int j = 0; j < 4; j++) {
    int co = co0 + j * 16;
    float bs = bias[co];
#pragma unroll
    for (int i = 0; i < 4; i++) {
#pragma unroll
      for (int r = 0; r < 4; r++) {
        float v = acc[i][j][r] + bs;
        size_t oi = ((size_t)(b * C_ + co) * NPIX + px0 + i * 16 + r);
        if (OUT_BF16) ((unsigned short*)outp)[oi] = f2bf(v);
        else ((float*)outp)[oi] = v;
      }
    }
  }
}

// ---------- instance norm + swish, in place, one block per (b,c) ----------
__global__ __launch_bounds__(256) void k_innorm(float* __restrict__ x) {
  __shared__ float s4[4];
  int bc = blockIdx.x;
  float* p = x + (size_t)bc * NPIX;
  int tid = threadIdx.x;
  int lane = tid & 63, w = tid >> 6;
  float v[16];
  float s = 0.f;
#pragma unroll
  for (int i = 0; i < 16; i++) { v[i] = p[tid + i * 256]; s += v[i]; }
  s = wave_reduce_sum(s);
  if (lane == 0) s4[w] = s;
  __syncthreads();
  float mean = (s4[0] + s4[1] + s4[2] + s4[3]) * (1.0f / 4096.0f);
  __syncthreads();
  float s2 = 0.f;
#pragma unroll
  for (int i = 0; i < 16; i++) { float d = v[i] - mean; s2 += d * d; }
  s2 = wave_reduce_sum(s2);
  if (lane == 0) s4[w] = s2;
  __syncthreads();
  float var = (s4[0] + s4[1] + s4[2] + s4[3]) * (1.0f / 4096.0f);
  float inv = 1.0f / sqrtf(var + 1e-5f);
#pragma unroll
  for (int i = 0; i < 16; i++) {
    float xn = (v[i] - mean) * inv;
    float sg = 1.0f / (1.0f + expf(-xn));
    p[tid + i * 256] = xn * sg;
  }
}

// ---------- per-pixel channel sum of squares of x_down ----------
__global__ __launch_bounds__(256) void k_sq32(const float* __restrict__ xd, float* __restrict__ sq) {
  int idx = blockIdx.x * 256 + threadIdx.x;
  if (idx >= B_ * NP) return;
  int pix = idx & 1023; int b = idx >> 10;
  const float* p = xd + (size_t)b * C_ * NP + pix;
  float s = 0.f;
  for (int c = 0; c < C_; c++) { float v = p[c * NP]; s += v * v; }
  sq[idx] = s;
}

// ---------- fq[q] = mm ? 1/max(norm,1e-4) : 0 ----------
__global__ __launch_bounds__(256) void k_normmm(const float* __restrict__ sq, const float* __restrict__ m32,
                                                float* __restrict__ fq) {
  int idx = blockIdx.x * 256 + threadIdx.x;
  if (idx >= B_ * NP) return;
  int q = idx & 1023, b = idx >> 10;
  int qi = q >> 5, qj = q & 31;
  float ns = 0.f, ms = 0.f;
#pragma unroll
  for (int k = 0; k < 3; k++)
#pragma unroll
    for (int l = 0; l < 3; l++) {
      int r = qi + k - 1, c = qj + l - 1;
      if (r >= 0 && r < 32 && c >= 0 && c < 32) {
        ns += sq[b * NP + r * 32 + c];
        ms += m32[b * NP + r * 32 + c];
      }
    }
  float f = (ms == 0.0f) ? (1.0f / fmaxf(sqrtf(ns), 1e-4f)) : 0.0f;
  fq[idx] = f;
}

// ---------- Gram: sc[b,p,q] = (pt_p . pt_q) * fq[q]  (implicit im2col, f32) ----------
__global__ __launch_bounds__(256) void k_gram(const float* __restrict__ xd, const float* __restrict__ fq,
                                              float* __restrict__ sc) {
  int bp = blockIdx.x, bq = blockIdx.y, b = blockIdx.z;
  int pi0 = bp * 2, qi0 = bq * 2;
  __shared__ float sA[544], sB[544];   // [c4][4 rows][34 cols]
  int tid = threadIdx.x;
  int tq = tid & 15, tp = tid >> 4;
  int p4 = tp * 4, q4 = tq * 4;
  int pil = p4 >> 5, pj0 = p4 & 31;
  int qil = q4 >> 5, qj0 = q4 & 31;
  float acc[4][4];
#pragma unroll
  for (int i = 0; i < 4; i++)
#pragma unroll
    for (int j = 0; j < 4; j++) acc[i][j] = 0.f;
  const float* xb = xd + (size_t)b * C_ * NP;
  for (int c0 = 0; c0 < 256; c0 += 4) {
    __syncthreads();
    for (int i = tid; i < 1088; i += 256) {
      int which = i >= 544;
      int j = which ? i - 544 : i;
      int cc = j / 136, rem = j % 136;
      int r = rem / 34, col = rem % 34;
      int gy = (which ? qi0 : pi0) + r - 1;
      int gx = col - 1;
      float v = 0.f;
      if (gy >= 0 && gy < 32 && gx >= 0 && gx < 32) v = xb[(size_t)(c0 + cc) * NP + gy * 32 + gx];
      float* dst = which ? sB : sA;
      dst[j] = v;
    }
    __syncthreads();
#pragma unroll
    for (int cc = 0; cc < 4; cc++) {
#pragma unroll
      for (int k = 0; k < 3; k++) {
        float ra[6], rb[6];
#pragma unroll
        for (int u = 0; u < 6; u++) ra[u] = sA[cc * 136 + (pil + k) * 34 + pj0 + u];
#pragma unroll
        for (int u = 0; u < 6; u++) rb[u] = sB[cc * 136 + (qil + k) * 34 + qj0 + u];
#pragma unroll
        for (int l = 0; l < 3; l++)
#pragma unroll
          for (int i2 = 0; i2 < 4; i2++)
#pragma unroll
            for (int j2 = 0; j2 < 4; j2++) acc[i2][j2] += ra[i2 + l] * rb[j2 + l];
      }
    }
  }
  int p0 = bp * 64 + p4, q0 = bq * 64 + q4;
#pragma unroll
  for (int i2 = 0; i2 < 4; i2++)
#pragma unroll
    for (int j2 = 0; j2 < 4; j2++) {
      int q = q0 + j2;
      sc[((size_t)b * NP + (p0 + i2)) * NP + q] = acc[i2][j2] * fq[b * NP + q];
    }
}

// ---------- softmax over q (axis=1) for each (b,p); att = softmax(10*s)*mm, clip 1e-8 ----------
__global__ __launch_bounds__(256) void k_softmax(float* __restrict__ sc, const float* __restrict__ fq) {
  __shared__ float s4[4];
  int row = blockIdx.x;        // b*1024 + p
  int b = row >> 10;
  float* r = sc + (size_t)row * NP;
  int tid = threadIdx.x;
  int lane = tid & 63, w = tid >> 6;
  float4 sv = *(const float4*)&r[tid * 4];
  float l0 = sv.x * 10.f, l1 = sv.y * 10.f, l2 = sv.z * 10.f, l3 = sv.w * 10.f;
  float mx = fmaxf(fmaxf(l0, l1), fmaxf(l2, l3));
  mx = wave_reduce_max(mx);
  if (lane == 0) s4[w] = mx;
  __syncthreads();
  float M = fmaxf(fmaxf(s4[0], s4[1]), fmaxf(s4[2], s4[3]));
  __syncthreads();
  float e0 = expf(l0 - M), e1 = expf(l1 - M), e2 = expf(l2 - M), e3 = expf(l3 - M);
  float s = e0 + e1 + e2 + e3;
  s = wave_reduce_sum(s);
  if (lane == 0) s4[w] = s;
  __syncthreads();
  float inv = 1.0f / (s4[0] + s4[1] + s4[2] + s4[3]);
  const float* fb = fq + b * NP + tid * 4;
  float m0 = fb[0] > 0.f ? 1.f : 0.f;
  float m1 = fb[1] > 0.f ? 1.f : 0.f;
  float m2 = fb[2] > 0.f ? 1.f : 0.f;
  float m3 = fb[3] > 0.f ? 1.f : 0.f;
  float a0 = fmaxf(e0 * inv * m0, 1e-8f);
  float a1 = fmaxf(e1 * inv * m1, 1e-8f);
  float a2 = fmaxf(e2 * inv * m2, 1e-8f);
  float a3 = fmaxf(e3 * inv * m3, 1e-8f);
  *(float4*)&r[tid * 4] = make_float4(a0, a1, a2, a3);
}

// ---------- out = x*(1-m64) ----------
__global__ __launch_bounds__(256) void k_initout(const float4* __restrict__ x, const float* __restrict__ m64,
                                                 float4* __restrict__ out) {
  int i = blockIdx.x * 256 + threadIdx.x;
  if (i >= (B_ * C_ * NPIX) / 4) return;
  int e = i * 4;
  int pix = e & (NPIX - 1);
  int b = e / (C_ * NPIX);
  const float4 mv = *(const float4*)&m64[b * NPIX + pix];
  float4 xv = x[i];
  out[i] = make_float4(xv.x * (1.f - mv.x), xv.y * (1.f - mv.y), xv.z * (1.f - mv.z), xv.w * (1.f - mv.w));
}

// ---------- F-GEMM + scatter: out += 0.25*m64 * sum_q att[p,q]*x_pad[co,2qi+ky-1,2qj+kx-1] ----------
__global__ __launch_bounds__(256) void k_fgemm(const float* __restrict__ att, const float* __restrict__ x,
                                               const float* __restrict__ m64, float* __restrict__ out) {
  int pt = blockIdx.x;
  int kk = blockIdx.y; int ky = kk >> 2, kx = kk & 3;
  int b = blockIdx.z;
  int tid = threadIdx.x;
  __shared__ float sA[1024];       // [p64][q16]
  __shared__ float sB[16 * 260];   // [q16][co256 pad 260]
  float acc[4][16];
#pragma unroll
  for (int i = 0; i < 4; i++)
#pragma unroll
    for (int j = 0; j < 16; j++) acc[i][j] = 0.f;
  const float* ab = att + ((size_t)b * NP + pt * 64) * NP;
  const float* xb = x + (size_t)b * C_ * NPIX;
  int tco = tid & 15, tpp = tid >> 4;
  for (int q0 = 0; q0 < 1024; q0 += 16) {
    __syncthreads();
    {
      int p = tid >> 2, qo = (tid & 3) * 4;
      float4 v = *(const float4*)(ab + (size_t)p * NP + q0 + qo);
      *(float4*)&sA[p * 16 + qo] = v;
    }
    {
      int qv = tid & 15, cob = tid >> 4;
      int q = q0 + qv; int qi = q >> 5, qj = q & 31;
      int gy = 2 * qi + ky - 1, gx = 2 * qj + kx - 1;
      bool inb = (gy >= 0 && gy < 64 && gx >= 0 && gx < 64);
      const float* xp = xb + gy * 64 + gx;
#pragma unroll
      for (int it = 0; it < 16; it++) {
        int co = cob + it * 16;
        sB[qv * 260 + co] = inb ? xp[(size_t)co * NPIX] : 0.f;
      }
    }
    __syncthreads();
#pragma unroll 4
    for (int qq = 0; qq < 16; qq++) {
      float a0 = sA[(tpp * 4 + 0) * 16 + qq];
      float a1 = sA[(tpp * 4 + 1) * 16 + qq];
      float a2 = sA[(tpp * 4 + 2) * 16 + qq];
      float a3 = sA[(tpp * 4 + 3) * 16 + qq];
#pragma unroll
      for (int j = 0; j < 16; j++) {
        float bv = sB[qq * 260 + tco + j * 16];
        acc[0][j] += a0 * bv;
        acc[1][j] += a1 * bv;
        acc[2][j] += a2 * bv;
        acc[3][j] += a3 * bv;
      }
    }
  }
#pragma unroll
  for (int i = 0; i < 4; i++) {
    int ploc = tpp * 4 + i;
    int p = pt * 64 + ploc;
    int pi = p >> 5, pj = p & 31;
    int oy = 2 * pi + ky - 1, ox = 2 * pj + kx - 1;
    if (oy < 0 || oy >= 64 || ox < 0 || ox >= 64) continue;
    float msc = 0.25f * m64[b * NPIX + oy * 64 + ox];
    if (msc == 0.0f) continue;
    float* ob = out + ((size_t)b * C_ + tco) * NPIX + oy * 64 + ox;
#pragma unroll
    for (int j = 0; j < 16; j++) {
      atomicAdd(ob + (size_t)j * 16 * NPIX, acc[i][j] * msc);
    }
  }
}

extern "C" void kernel_launch(void* const* d_in, const int* in_sizes, int n_in,
                              void* d_out, int out_size, void* d_ws, size_t ws_size,
                              hipStream_t stream) {
  const float* bg   = (const float*)d_in[0];
  const float* fg   = (const float*)d_in[1];
  const float* mask = (const float*)d_in[2];
  const float* Wc   = (const float*)d_in[3];
  const float* bc   = (const float*)d_in[4];
  const float* Wm   = (const float*)d_in[5];
  const float* bm   = (const float*)d_in[6];
  const float* Wf   = (const float*)d_in[7];
  const float* bf   = (const float*)d_in[8];
  float* out = (float*)d_out;
  float* w = (float*)d_ws;

  // workspace layout (float offsets)
  float* mask64 = w;                          // 32768
  float* mask32 = w + 32768;                  // 8192
  float* sq32   = w + 40960;                  // 8192
  float* fq     = w + 49152;                  // 8192
  float* bias1  = w + 57344;                  // 256 (pad to 65536)
  float* SumAtt = w + 65536;                  // 8388608 f32 (gram/att) -- aliases A0b/A1b
  unsigned short* A0b = (unsigned short*)(w + 65536);            // 8388608 bf16
  unsigned short* A1b = (unsigned short*)(w + 65536 + 4194304);  // 8388608 bf16
  unsigned short* tbuf = (unsigned short*)(w + 8454144);         // 8388608 bf16 -- later aliased by xd
  float* xd     = w + 8454144;                // 2097152 f32 (after conv2 done)
  float* xbuf   = w + 12648448;               // 8388608 f32
  unsigned short* Wp1 = (unsigned short*)(w + 21037056);         // 18*65536 bf16
  unsigned short* Wp2 = (unsigned short*)(w + 21626880);         // 9*65536 bf16
  // total ~21.93M floats = 87.7 MB

  // mask 256 -> 64
  hipLaunchKernelGGL(k_resize, dim3(128), dim3(256), 0, stream, mask, mask64, 256, 256, 64, 64, 32768);
  // weight prep + bias
  hipLaunchKernelGGL(k_wprep, dim3(6912), dim3(256), 0, stream, Wc, Wm, Wf, Wp1, Wp2);
  hipLaunchKernelGGL(k_bias, dim3(1), dim3(256), 0, stream, bc, bm, bias1);
  // A prep (fg+bg masked, bf16)
  hipLaunchKernelGGL(k_prepA, dim3(8192), dim3(256), 0, stream, fg, bg, mask64, A0b, A1b);
  // conv1 (dual masked conv, K=4608) -> tbuf bf16
  hipLaunchKernelGGL((k_conv_mfma<18, true>), dim3(32, 2, 8), dim3(256), 0, stream, A0b, A1b, Wp1, bias1, (void*)tbuf);
  // conv2 (K=2304) -> xbuf f32
  hipLaunchKernelGGL((k_conv_mfma<9, false>), dim3(32, 2, 8), dim3(256), 0, stream, tbuf, tbuf, Wp2, bf, (void*)xbuf);
  // instance norm + swish in place
  hipLaunchKernelGGL(k_innorm, dim3(B_ * C_), dim3(256), 0, stream, xbuf);
  // x -> x_down (64 -> 32)  (overwrites tbuf region; tbuf is dead)
  hipLaunchKernelGGL(k_resize, dim3(8192), dim3(256), 0, stream, xbuf, xd, 64, 64, 32, 32, B_ * C_ * NP);
  // mask64 -> mask32
  hipLaunchKernelGGL(k_resize, dim3(32), dim3(256), 0, stream, mask64, mask32, 64, 64, 32, 32, B_ * NP);
  // per-pixel channel sumsq of x_down
  hipLaunchKernelGGL(k_sq32, dim3(32), dim3(256), 0, stream, xd, sq32);
  // fq = mm / max(norm,1e-4)
  hipLaunchKernelGGL(k_normmm, dim3(32), dim3(256), 0, stream, sq32, mask32, fq);
  // Gram -> score_t[b,p,q] (into SumAtt; A0b/A1b dead)
  hipLaunchKernelGGL(k_gram, dim3(16, 16, 8), dim3(256), 0, stream, xd, fq, SumAtt);
  // softmax over q, in place -> att_t[b,p,q]
  hipLaunchKernelGGL(k_softmax, dim3(B_ * NP), dim3(256), 0, stream, SumAtt, fq);
  // out = x*(1-m)
  hipLaunchKernelGGL(k_initout, dim3(8192), dim3(256), 0, stream, (const float4*)xbuf, mask64, (float4*)out);
  // F-GEMM + scatter: out += 0.25*m*conv_transpose(att, raw_w)
  hipLaunchKernelGGL(k_fgemm, dim3(16, 16, 8), dim3(256), 0, stream, SumAtt, xbuf, mask64, out);
}

// Round 3
// 1139.372 us; speedup vs baseline: 8.5923x; 2.1235x over previous
//
#include <hip/hip_runtime.h>
#include <math.h>

#define B_ 8
#define C_ 256
#define NPIX 4096      // 64*64
#define NP 1024        // 32*32

typedef __attribute__((ext_vector_type(8))) short bf16x8;
typedef __attribute__((ext_vector_type(4))) float f32x4;

__device__ __forceinline__ unsigned short f2bf(float f) {
  unsigned int u = __float_as_uint(f);
  unsigned int r = (u + 0x7FFFu + ((u >> 16) & 1u)) >> 16;
  return (unsigned short)r;
}
__device__ __forceinline__ unsigned int pk2(unsigned short lo, unsigned short hi) {
  return (unsigned int)lo | ((unsigned int)hi << 16);
}

// ---------- reductions ----------
__device__ __forceinline__ float wave_reduce_sum(float v) {
#pragma unroll
  for (int off = 32; off > 0; off >>= 1) v += __shfl_down(v, off, 64);
  return v;
}
__device__ __forceinline__ float wave_reduce_max(float v) {
#pragma unroll
  for (int off = 32; off > 0; off >>= 1) v = fmaxf(v, __shfl_down(v, off, 64));
  return v;
}

// ---------- bilinear resize, align_corners=True, bit-exact f32 linspace ----------
__global__ __launch_bounds__(256) void k_resize(const float* __restrict__ in, float* __restrict__ out,
                                                int IH, int IW, int OH, int OW, int nElem) {
  int idx = blockIdx.x * 256 + threadIdx.x;
  if (idx >= nElem) return;
  int ox = idx % OW; int t = idx / OW; int oy = t % OH; int bc = t / OH;
  float dy = (float)(IH - 1) / (float)(OH - 1);
  float dx = (float)(IW - 1) / (float)(OW - 1);
  float yf = (float)oy * dy;
  float xf = (float)ox * dx;
  float y0f = floorf(yf), x0f = floorf(xf);
  int y0 = (int)y0f, x0 = (int)x0f;
  int y1 = min(y0 + 1, IH - 1), x1 = min(x0 + 1, IW - 1);
  float wy = yf - y0f, wx = xf - x0f;
  const float* p = in + (size_t)bc * IH * IW;
  float a = p[y0 * IW + x0], b = p[y0 * IW + x1];
  float c = p[y1 * IW + x0], d = p[y1 * IW + x1];
  float top = a * (1.0f - wx) + b * wx;
  float bot = c * (1.0f - wx) + d * wx;
  out[idx] = top * (1.0f - wy) + bot * wy;
}

// ---------- weight prep: Wc,Wm -> Wp1[kk 0..17][co][ci] bf16; Wf -> Wp2[kk 0..8][co][ci] ----------
__global__ __launch_bounds__(256) void k_wprep(const float* __restrict__ Wc, const float* __restrict__ Wm,
                                               const float* __restrict__ Wf,
                                               unsigned short* __restrict__ Wp1, unsigned short* __restrict__ Wp2) {
  int idx = blockIdx.x * 256 + threadIdx.x;
  if (idx >= 3 * 589824) return;
  int part = idx / 589824;            // 0=Wc 1=Wm 2=Wf
  int rem = idx % 589824;             // kk*65536 + co*256 + ci
  int kk = rem >> 16, co = (rem >> 8) & 255, ci = rem & 255;
  const float* W = (part == 0) ? Wc : (part == 1) ? Wm : Wf;
  unsigned short o = f2bf(W[(size_t)co * 2304 + ci * 9 + kk]);
  if (part == 0) Wp1[rem] = o;
  else if (part == 1) Wp1[589824 + rem] = o;
  else Wp2[rem] = o;
}

__global__ __launch_bounds__(256) void k_bias(const float* __restrict__ bc, const float* __restrict__ bm,
                                              float* __restrict__ bias1) {
  int i = threadIdx.x;
  bias1[i] = bc[i] + bm[i];
}

// ---------- A prep: A0 = bf16((fg+bg)*(1-m)), A1 = bf16((fg+bg)*m), layout [b][ci][pix] ----------
__global__ __launch_bounds__(256) void k_prepA(const float* __restrict__ fg, const float* __restrict__ bg,
                                               const float* __restrict__ m64,
                                               unsigned short* __restrict__ A0, unsigned short* __restrict__ A1) {
  int i = blockIdx.x * 256 + threadIdx.x;
  if (i >= (B_ * C_ * NPIX) / 4) return;
  int e = i * 4;
  int pix = e & (NPIX - 1);
  int b = e >> 20;                      // 256*4096 = 2^20
  float4 f = ((const float4*)fg)[i];
  float4 g = ((const float4*)bg)[i];
  float4 m = *(const float4*)&m64[(b << 12) + pix];
  float s0 = f.x + g.x, s1 = f.y + g.y, s2 = f.z + g.z, s3 = f.w + g.w;
  uint2 a0, a1;
  a0.x = pk2(f2bf(s0 * (1.f - m.x)), f2bf(s1 * (1.f - m.y)));
  a0.y = pk2(f2bf(s2 * (1.f - m.z)), f2bf(s3 * (1.f - m.w)));
  a1.x = pk2(f2bf(s0 * m.x), f2bf(s1 * m.y));
  a1.y = pk2(f2bf(s2 * m.z), f2bf(s3 * m.w));
  ((uint2*)A0)[i] = a0;
  ((uint2*)A1)[i] = a1;
}

// ---------- MFMA implicit-GEMM conv ----------
__device__ __forceinline__ int swz(int row, int slot) {
  return row * 32 + ((slot ^ (row & 3) ^ ((row >> 2) & 3)) << 3);   // ushort units
}

template <int NKK, bool OUT_BF16>
__global__ __launch_bounds__(256) void k_conv_mfma(const unsigned short* __restrict__ A0,
                                                   const unsigned short* __restrict__ A1,
                                                   const unsigned short* __restrict__ Wp,
                                                   const float* __restrict__ bias,
                                                   void* __restrict__ outp) {
  __shared__ __align__(16) unsigned short Alds[4096];   // [128 pix][32 ci] swizzled
  __shared__ __align__(16) unsigned short Blds[4096];   // [128 co ][32 ci] swizzled
  int bp = blockIdx.x, cot = blockIdx.y, b = blockIdx.z;
  int tid = threadIdx.x;
  int lane = tid & 63, wave = tid >> 6;
  int wm = wave >> 1, wn = wave & 1;
  f32x4 acc[4][4];
#pragma unroll
  for (int i = 0; i < 4; i++)
#pragma unroll
    for (int j = 0; j < 4; j++) acc[i][j] = (f32x4){0.f, 0.f, 0.f, 0.f};

  int sp = tid & 127;      // A: pixel-in-tile; B: co-in-tile
  int hg = tid >> 7;       // ci half (16 each)
  int pr = sp >> 6, pc = sp & 63;
  int y0 = bp * 2;

  for (int kk = 0; kk < NKK; ++kk) {
    int kw = (kk < 9) ? kk : kk - 9;
    int ky = kw / 3, kx = kw % 3;
    const unsigned short* Asrc = (NKK == 18 && kk >= 9) ? A1 : A0;
    int gy = y0 + pr + ky - 1, gx = pc + kx - 1;
    bool valid = (gy >= 0 && gy < 64 && gx >= 0 && gx < 64);
    const unsigned short* abase = Asrc + ((size_t)b * C_ * NPIX + gy * 64 + gx);
    const unsigned short* wbase = Wp + ((size_t)(kk * 256 + cot * 128 + sp) * 256 + hg * 16);

    for (int ci0 = 0; ci0 < 256; ci0 += 32) {
      __syncthreads();
      unsigned short av[16];
#pragma unroll
      for (int j = 0; j < 16; j++) {
        int ci = ci0 + hg * 16 + j;
        av[j] = valid ? abase[(size_t)ci * NPIX] : (unsigned short)0;
      }
      {
        uint4 w0 = {pk2(av[0], av[1]), pk2(av[2], av[3]), pk2(av[4], av[5]), pk2(av[6], av[7])};
        uint4 w1 = {pk2(av[8], av[9]), pk2(av[10], av[11]), pk2(av[12], av[13]), pk2(av[14], av[15])};
        *(uint4*)&Alds[swz(sp, hg * 2 + 0)] = w0;
        *(uint4*)&Alds[swz(sp, hg * 2 + 1)] = w1;
      }
      {
        uint4 b0 = *(const uint4*)(wbase + ci0);
        uint4 b1 = *(const uint4*)(wbase + ci0 + 8);
        *(uint4*)&Blds[swz(sp, hg * 2 + 0)] = b0;
        *(uint4*)&Blds[swz(sp, hg * 2 + 1)] = b1;
      }
      __syncthreads();
      int slot = lane >> 4;
      int mr = wm * 64 + (lane & 15);
      int nc = wn * 64 + (lane & 15);
      bf16x8 af[4], bfr[4];
#pragma unroll
      for (int i = 0; i < 4; i++) af[i] = *(const bf16x8*)&Alds[swz(mr + i * 16, slot)];
#pragma unroll
      for (int j = 0; j < 4; j++) bfr[j] = *(const bf16x8*)&Blds[swz(nc + j * 16, slot)];
#pragma unroll
      for (int i = 0; i < 4; i++)
#pragma unroll
        for (int j = 0; j < 4; j++)
          acc[i][j] = __builtin_amdgcn_mfma_f32_16x16x32_bf16(af[i], bfr[j], acc[i][j], 0, 0, 0);
    }
  }
  int co0 = cot * 128 + wn * 64 + (lane & 15);
  int px0 = bp * 128 + wm * 64 + ((lane >> 4) << 2);
#pragma unroll
  for (int j = 0; j < 4; j++) {
    int co = co0 + j * 16;
    float bs = bias[co];
#pragma unroll
    for (int i = 0; i < 4; i++) {
#pragma unroll
      for (int r = 0; r < 4; r++) {
        float v = acc[i][j][r] + bs;
        size_t oi = ((size_t)(b * C_ + co) * NPIX + px0 + i * 16 + r);
        if (OUT_BF16) ((unsigned short*)outp)[oi] = f2bf(v);
        else ((float*)outp)[oi] = v;
      }
    }
  }
}

// ---------- instance norm + swish ----------
__global__ __launch_bounds__(256) void k_innorm(float* __restrict__ x) {
  __shared__ float s4[4];
  int bc = blockIdx.x;
  float* p = x + (size_t)bc * NPIX;
  int tid = threadIdx.x;
  int lane = tid & 63, w = tid >> 6;
  float v[16];
  float s = 0.f;
#pragma unroll
  for (int i = 0; i < 16; i++) { v[i] = p[tid + i * 256]; s += v[i]; }
  s = wave_reduce_sum(s);
  if (lane == 0) s4[w] = s;
  __syncthreads();
  float mean = (s4[0] + s4[1] + s4[2] + s4[3]) * (1.0f / 4096.0f);
  __syncthreads();
  float s2 = 0.f;
#pragma unroll
  for (int i = 0; i < 16; i++) { float d = v[i] - mean; s2 += d * d; }
  s2 = wave_reduce_sum(s2);
  if (lane == 0) s4[w] = s2;
  __syncthreads();
  float var = (s4[0] + s4[1] + s4[2] + s4[3]) * (1.0f / 4096.0f);
  float inv = 1.0f / sqrtf(var + 1e-5f);
#pragma unroll
  for (int i = 0; i < 16; i++) {
    float xn = (v[i] - mean) * inv;
    float sg = 1.0f / (1.0f + expf(-xn));
    p[tid + i * 256] = xn * sg;
  }
}

// ---------- f32 -> bf16 copies ----------
__global__ __launch_bounds__(256) void k_f2bf4(const float4* __restrict__ in, uint2* __restrict__ outb, int n4) {
  int i = blockIdx.x * 256 + threadIdx.x;
  if (i >= n4) return;
  float4 v = in[i];
  uint2 o;
  o.x = pk2(f2bf(v.x), f2bf(v.y));
  o.y = pk2(f2bf(v.z), f2bf(v.w));
  outb[i] = o;
}

// ---------- per-pixel channel sum of squares of x_down ----------
__global__ __launch_bounds__(256) void k_sq32(const float* __restrict__ xd, float* __restrict__ sq) {
  int idx = blockIdx.x * 256 + threadIdx.x;
  if (idx >= B_ * NP) return;
  int pix = idx & 1023; int b = idx >> 10;
  const float* p = xd + (size_t)b * C_ * NP + pix;
  float s = 0.f;
  for (int c = 0; c < C_; c++) { float v = p[c * NP]; s += v * v; }
  sq[idx] = s;
}

// ---------- fq[q] = mm ? 1/max(norm,1e-4) : 0 ----------
__global__ __launch_bounds__(256) void k_normmm(const float* __restrict__ sq, const float* __restrict__ m32,
                                                float* __restrict__ fq) {
  int idx = blockIdx.x * 256 + threadIdx.x;
  if (idx >= B_ * NP) return;
  int q = idx & 1023, b = idx >> 10;
  int qi = q >> 5, qj = q & 31;
  float ns = 0.f, ms = 0.f;
#pragma unroll
  for (int k = 0; k < 3; k++)
#pragma unroll
    for (int l = 0; l < 3; l++) {
      int r = qi + k - 1, c = qj + l - 1;
      if (r >= 0 && r < 32 && c >= 0 && c < 32) {
        ns += sq[b * NP + r * 32 + c];
        ms += m32[b * NP + r * 32 + c];
      }
    }
  float f = (ms == 0.0f) ? (1.0f / fmaxf(sqrtf(ns), 1e-4f)) : 0.0f;
  fq[idx] = f;
}

// ---------- Gram MFMA: sc[b,p,q] = (pt_p . pt_q) * fq[q], implicit im2col over 9 shifts x 256 ci ----------
__global__ __launch_bounds__(256) void k_gram_mfma(const unsigned short* __restrict__ xdb,
                                                   const float* __restrict__ fq,
                                                   float* __restrict__ sc) {
  __shared__ __align__(16) unsigned short Alds[4096];   // [128 p][32 ci] swizzled
  __shared__ __align__(16) unsigned short Blds[4096];   // [128 q][32 ci] swizzled
  int bp = blockIdx.x, bq = blockIdx.y, b = blockIdx.z;
  int tid = threadIdx.x;
  int lane = tid & 63, wave = tid >> 6;
  int wm = wave >> 1, wn = wave & 1;
  f32x4 acc[4][4];
#pragma unroll
  for (int i = 0; i < 4; i++)
#pragma unroll
    for (int j = 0; j < 4; j++) acc[i][j] = (f32x4){0.f, 0.f, 0.f, 0.f};

  int sp = tid & 127;
  int hg = tid >> 7;
  int pA = bp * 128 + sp, piA = pA >> 5, pjA = pA & 31;
  int pB = bq * 128 + sp, piB = pB >> 5, pjB = pB & 31;
  const unsigned short* xb = xdb + (size_t)b * C_ * NP;

  for (int kk = 0; kk < 9; ++kk) {
    int dy = kk / 3 - 1, dx = kk % 3 - 1;
    int gyA = piA + dy, gxA = pjA + dx;
    int gyB = piB + dy, gxB = pjB + dx;
    bool vA = (gyA >= 0 && gyA < 32 && gxA >= 0 && gxA < 32);
    bool vB = (gyB >= 0 && gyB < 32 && gxB >= 0 && gxB < 32);
    const unsigned short* baseA = xb + gyA * 32 + gxA;
    const unsigned short* baseB = xb + gyB * 32 + gxB;
    for (int ci0 = 0; ci0 < 256; ci0 += 32) {
      __syncthreads();
      unsigned short av[16], bv[16];
#pragma unroll
      for (int j = 0; j < 16; j++) {
        int ci = ci0 + hg * 16 + j;
        av[j] = vA ? baseA[(size_t)ci * NP] : (unsigned short)0;
        bv[j] = vB ? baseB[(size_t)ci * NP] : (unsigned short)0;
      }
      {
        uint4 w0 = {pk2(av[0], av[1]), pk2(av[2], av[3]), pk2(av[4], av[5]), pk2(av[6], av[7])};
        uint4 w1 = {pk2(av[8], av[9]), pk2(av[10], av[11]), pk2(av[12], av[13]), pk2(av[14], av[15])};
        *(uint4*)&Alds[swz(sp, hg * 2 + 0)] = w0;
        *(uint4*)&Alds[swz(sp, hg * 2 + 1)] = w1;
        uint4 u0 = {pk2(bv[0], bv[1]), pk2(bv[2], bv[3]), pk2(bv[4], bv[5]), pk2(bv[6], bv[7])};
        uint4 u1 = {pk2(bv[8], bv[9]), pk2(bv[10], bv[11]), pk2(bv[12], bv[13]), pk2(bv[14], bv[15])};
        *(uint4*)&Blds[swz(sp, hg * 2 + 0)] = u0;
        *(uint4*)&Blds[swz(sp, hg * 2 + 1)] = u1;
      }
      __syncthreads();
      int slot = lane >> 4;
      int mr = wm * 64 + (lane & 15);
      int nc = wn * 64 + (lane & 15);
      bf16x8 af[4], bfr[4];
#pragma unroll
      for (int i = 0; i < 4; i++) af[i] = *(const bf16x8*)&Alds[swz(mr + i * 16, slot)];
#pragma unroll
      for (int j = 0; j < 4; j++) bfr[j] = *(const bf16x8*)&Blds[swz(nc + j * 16, slot)];
#pragma unroll
      for (int i = 0; i < 4; i++)
#pragma unroll
        for (int j = 0; j < 4; j++)
          acc[i][j] = __builtin_amdgcn_mfma_f32_16x16x32_bf16(af[i], bfr[j], acc[i][j], 0, 0, 0);
    }
  }
  // D: m(p) rows of A, n(q) rows of B
  int q0 = bq * 128 + wn * 64 + (lane & 15);
  int p0 = bp * 128 + wm * 64 + ((lane >> 4) << 2);
#pragma unroll
  for (int j = 0; j < 4; j++) {
    int q = q0 + j * 16;
    float f = fq[b * NP + q];
#pragma unroll
    for (int i = 0; i < 4; i++)
#pragma unroll
      for (int r = 0; r < 4; r++)
        sc[((size_t)b * NP + (p0 + i * 16 + r)) * NP + q] = acc[i][j][r] * f;
  }
}

// ---------- softmax over q for each (b,p); emits att in bf16 ----------
__global__ __launch_bounds__(256) void k_softmax(const float* __restrict__ sc, const float* __restrict__ fq,
                                                 unsigned short* __restrict__ attb) {
  __shared__ float s4[4];
  int row = blockIdx.x;        // b*1024 + p
  int b = row >> 10;
  const float* r = sc + (size_t)row * NP;
  int tid = threadIdx.x;
  int lane = tid & 63, w = tid >> 6;
  float4 sv = *(const float4*)&r[tid * 4];
  float l0 = sv.x * 10.f, l1 = sv.y * 10.f, l2 = sv.z * 10.f, l3 = sv.w * 10.f;
  float mx = fmaxf(fmaxf(l0, l1), fmaxf(l2, l3));
  mx = wave_reduce_max(mx);
  if (lane == 0) s4[w] = mx;
  __syncthreads();
  float M = fmaxf(fmaxf(s4[0], s4[1]), fmaxf(s4[2], s4[3]));
  __syncthreads();
  float e0 = expf(l0 - M), e1 = expf(l1 - M), e2 = expf(l2 - M), e3 = expf(l3 - M);
  float s = e0 + e1 + e2 + e3;
  s = wave_reduce_sum(s);
  if (lane == 0) s4[w] = s;
  __syncthreads();
  float inv = 1.0f / (s4[0] + s4[1] + s4[2] + s4[3]);
  const float* fb = fq + b * NP + tid * 4;
  float m0 = fb[0] > 0.f ? 1.f : 0.f;
  float m1 = fb[1] > 0.f ? 1.f : 0.f;
  float m2 = fb[2] > 0.f ? 1.f : 0.f;
  float m3 = fb[3] > 0.f ? 1.f : 0.f;
  float a0 = fmaxf(e0 * inv * m0, 1e-8f);
  float a1 = fmaxf(e1 * inv * m1, 1e-8f);
  float a2 = fmaxf(e2 * inv * m2, 1e-8f);
  float a3 = fmaxf(e3 * inv * m3, 1e-8f);
  uint2 o;
  o.x = pk2(f2bf(a0), f2bf(a1));
  o.y = pk2(f2bf(a2), f2bf(a3));
  *(uint2*)&attb[(size_t)row * NP + tid * 4] = o;
}

// ---------- PV^T class-GEMM: per parity class, D[co,o] = sum_{t,q} x_shift[co,q] * att[p_t(o),q]
//            epilogue: out = 0.25*m*D + x*(1-m)  (atomic-free, single write) ----------
__global__ __launch_bounds__(256) void k_pv(const unsigned short* __restrict__ attb,
                                            const unsigned short* __restrict__ xb16,
                                            const float* __restrict__ xbuf,
                                            const float* __restrict__ m64,
                                            float* __restrict__ out) {
  __shared__ __align__(16) unsigned short Alds[4096];   // [128 co][32 q] swizzled
  __shared__ __align__(16) unsigned short Blds[4096];   // [128 o ][32 q] swizzled
  int bn = blockIdx.x, bm = blockIdx.y;
  int z = blockIdx.z;
  int b = z >> 2, cls = z & 3, cy = cls >> 1, cx = cls & 1;
  int tid = threadIdx.x;
  int lane = tid & 63, wave = tid >> 6;
  int wm = wave >> 1, wn = wave & 1;
  f32x4 acc[4][4];
#pragma unroll
  for (int i = 0; i < 4; i++)
#pragma unroll
    for (int j = 0; j < 4; j++) acc[i][j] = (f32x4){0.f, 0.f, 0.f, 0.f};

  // per-class t-tables: ky/kx and p-offsets
  int kyT0 = (cy == 0) ? 1 : 2, kyT1 = (cy == 0) ? 3 : 0;
  int pioT0 = 0, pioT1 = (cy == 0) ? -1 : 1;
  int kxT0 = (cx == 0) ? 1 : 2, kxT1 = (cx == 0) ? 3 : 0;
  int pjoT0 = 0, pjoT1 = (cx == 0) ? -1 : 1;

  int sp = tid & 127;
  int hg = tid >> 7;
  int coA = bm * 128 + sp;                       // A row: co
  int oB = bn * 128 + sp;                        // B row: o
  int oyh = oB >> 5, oxh = oB & 31;
  const unsigned short* xrow = xb16 + (size_t)(b * C_ + coA) * NPIX;
  const unsigned short* attB = attb + (size_t)b * NP * NP;

  for (int chunk = 0; chunk < 128; ++chunk) {
    int t = chunk >> 5;                          // 0..3 = (ty,tx)
    int ty = t >> 1, tx = t & 1;
    int qi = chunk & 31;                         // q-chunk = row qi, qj 0..31
    int q0 = qi * 32;
    int ky = ty ? kyT1 : kyT0;
    int kx = tx ? kxT1 : kxT0;
    __syncthreads();
    // --- A stage: x[co, 2qi+ky-1, 2qj+kx-1], qj = hg*16+u ---
    {
      int gy = 2 * qi + ky - 1;
      bool vy = (gy >= 0 && gy < 64);
      const unsigned short* arow = xrow + gy * 64;
      unsigned short av[16];
#pragma unroll
      for (int u = 0; u < 16; u++) {
        int gx = 2 * (hg * 16 + u) + kx - 1;
        av[u] = (vy && gx >= 0 && gx < 64) ? arow[gx] : (unsigned short)0;
      }
      uint4 w0 = {pk2(av[0], av[1]), pk2(av[2], av[3]), pk2(av[4], av[5]), pk2(av[6], av[7])};
      uint4 w1 = {pk2(av[8], av[9]), pk2(av[10], av[11]), pk2(av[12], av[13]), pk2(av[14], av[15])};
      *(uint4*)&Alds[swz(sp, hg * 2 + 0)] = w0;
      *(uint4*)&Alds[swz(sp, hg * 2 + 1)] = w1;
    }
    // --- B stage: att[p_t(o), q0+hg*16 .. +16] (vectorized) ---
    {
      int pi = oyh + (ty ? pioT1 : pioT0);
      int pj = oxh + (tx ? pjoT1 : pjoT0);
      bool vB = (pi >= 0 && pi < 32 && pj >= 0 && pj < 32);
      uint4 b0 = {0, 0, 0, 0}, b1 = {0, 0, 0, 0};
      if (vB) {
        const unsigned short* ab = attB + (size_t)(pi * 32 + pj) * NP + q0 + hg * 16;
        b0 = *(const uint4*)(ab);
        b1 = *(const uint4*)(ab + 8);
      }
      *(uint4*)&Blds[swz(sp, hg * 2 + 0)] = b0;
      *(uint4*)&Blds[swz(sp, hg * 2 + 1)] = b1;
    }
    __syncthreads();
    int slot = lane >> 4;
    int mr = wm * 64 + (lane & 15);
    int nc = wn * 64 + (lane & 15);
    bf16x8 af[4], bfr[4];
#pragma unroll
    for (int i = 0; i < 4; i++) af[i] = *(const bf16x8*)&Alds[swz(mr + i * 16, slot)];
#pragma unroll
    for (int j = 0; j < 4; j++) bfr[j] = *(const bf16x8*)&Blds[swz(nc + j * 16, slot)];
#pragma unroll
    for (int i = 0; i < 4; i++)
#pragma unroll
      for (int j = 0; j < 4; j++)
        acc[i][j] = __builtin_amdgcn_mfma_f32_16x16x32_bf16(af[i], bfr[j], acc[i][j], 0, 0, 0);
  }
  // epilogue: m = co, n = o; blend with x
  int co0 = bm * 128 + wm * 64 + ((lane >> 4) << 2);
  int o0 = bn * 128 + wn * 64 + (lane & 15);
#pragma unroll
  for (int j = 0; j < 4; j++) {
    int o = o0 + j * 16;
    int oy = ((o >> 5) << 1) + cy, ox = ((o & 31) << 1) + cx;
    int opix = oy * 64 + ox;
    float msk = m64[b * NPIX + opix];
    float s = 0.25f * msk, t1m = 1.0f - msk;
#pragma unroll
    for (int i = 0; i < 4; i++) {
#pragma unroll
      for (int r = 0; r < 4; r++) {
        int co = co0 + i * 16 + r;
        size_t xi = (size_t)(b * C_ + co) * NPIX + opix;
        out[xi] = acc[i][j][r] * s + xbuf[xi] * t1m;
      }
    }
  }
}

extern "C" void kernel_launch(void* const* d_in, const int* in_sizes, int n_in,
                              void* d_out, int out_size, void* d_ws, size_t ws_size,
                              hipStream_t stream) {
  const float* bg   = (const float*)d_in[0];
  const float* fg   = (const float*)d_in[1];
  const float* mask = (const float*)d_in[2];
  const float* Wc   = (const float*)d_in[3];
  const float* bc   = (const float*)d_in[4];
  const float* Wm   = (const float*)d_in[5];
  const float* bm   = (const float*)d_in[6];
  const float* Wf   = (const float*)d_in[7];
  const float* bf   = (const float*)d_in[8];
  float* out = (float*)d_out;
  float* w = (float*)d_ws;

  // workspace layout (float offsets), total 26,116,096 floats = 104.5 MB
  float* mask64 = w;                          // 32768
  float* mask32 = w + 32768;                  // 8192
  float* sq32   = w + 40960;                  // 8192
  float* fq     = w + 49152;                  // 8192
  float* bias1  = w + 57344;                  // 256 (pad to 65536)
  // region1 [65536, 8454144): A0b+A1b bf16 during convs; sc f32 afterwards
  unsigned short* A0b = (unsigned short*)(w + 65536);
  unsigned short* A1b = (unsigned short*)(w + 65536 + 4194304);
  float* sc = w + 65536;
  // region2 [8454144, 12648448): tbuf bf16 -> xd f32 + xdb bf16 -> att_bf bf16
  unsigned short* tbuf = (unsigned short*)(w + 8454144);
  float* xd = w + 8454144;                    // 2097152 floats
  unsigned short* xdb = (unsigned short*)(w + 10551296);  // 2097152 bf16
  unsigned short* attb = (unsigned short*)(w + 8454144);  // 8388608 bf16 (after gram)
  float* xbuf = w + 12648448;                 // 8388608
  unsigned short* Wp1 = (unsigned short*)(w + 21037056);  // 18*65536 bf16
  unsigned short* Wp2 = (unsigned short*)(w + 21626880);  // 9*65536 bf16
  unsigned short* xb16 = (unsigned short*)(w + 21921792); // 8388608 bf16

  // mask 256 -> 64
  hipLaunchKernelGGL(k_resize, dim3(128), dim3(256), 0, stream, mask, mask64, 256, 256, 64, 64, 32768);
  // weight prep + bias
  hipLaunchKernelGGL(k_wprep, dim3(6912), dim3(256), 0, stream, Wc, Wm, Wf, Wp1, Wp2);
  hipLaunchKernelGGL(k_bias, dim3(1), dim3(256), 0, stream, bc, bm, bias1);
  // A prep (fg+bg masked, bf16)
  hipLaunchKernelGGL(k_prepA, dim3(8192), dim3(256), 0, stream, fg, bg, mask64, A0b, A1b);
  // conv1 (dual masked conv, K=4608) -> tbuf bf16
  hipLaunchKernelGGL((k_conv_mfma<18, true>), dim3(32, 2, 8), dim3(256), 0, stream, A0b, A1b, Wp1, bias1, (void*)tbuf);
  // conv2 (K=2304) -> xbuf f32
  hipLaunchKernelGGL((k_conv_mfma<9, false>), dim3(32, 2, 8), dim3(256), 0, stream, tbuf, tbuf, Wp2, bf, (void*)xbuf);
  // instance norm + swish in place
  hipLaunchKernelGGL(k_innorm, dim3(B_ * C_), dim3(256), 0, stream, xbuf);
  // x -> bf16 (for PV)
  hipLaunchKernelGGL(k_f2bf4, dim3(8192), dim3(256), 0, stream, (const float4*)xbuf, (uint2*)xb16, (B_ * C_ * NPIX) / 4);
  // x -> x_down (64 -> 32)
  hipLaunchKernelGGL(k_resize, dim3(8192), dim3(256), 0, stream, xbuf, xd, 64, 64, 32, 32, B_ * C_ * NP);
  // mask64 -> mask32
  hipLaunchKernelGGL(k_resize, dim3(32), dim3(256), 0, stream, mask64, mask32, 64, 64, 32, 32, B_ * NP);
  // x_down -> bf16 (for gram)
  hipLaunchKernelGGL(k_f2bf4, dim3(2048), dim3(256), 0, stream, (const float4*)xd, (uint2*)xdb, (B_ * C_ * NP) / 4);
  // per-pixel channel sumsq of x_down
  hipLaunchKernelGGL(k_sq32, dim3(32), dim3(256), 0, stream, xd, sq32);
  // fq = mm / max(norm,1e-4)
  hipLaunchKernelGGL(k_normmm, dim3(32), dim3(256), 0, stream, sq32, mask32, fq);
  // Gram MFMA -> sc[b,p,q] (A0b/A1b dead)
  hipLaunchKernelGGL(k_gram_mfma, dim3(8, 8, 8), dim3(256), 0, stream, xdb, fq, sc);
  // softmax over q -> att bf16 (xd/xdb dead)
  hipLaunchKernelGGL(k_softmax, dim3(B_ * NP), dim3(256), 0, stream, sc, fq, attb);
  // PV class-GEMM + blend -> out
  hipLaunchKernelGGL(k_pv, dim3(8, 2, 32), dim3(256), 0, stream, attb, xb16, xbuf, mask64, out);
}

// Round 6
// 540.601 us; speedup vs baseline: 18.1091x; 2.1076x over previous
//
#include <hip/hip_runtime.h>
#include <math.h>

#define B_ 8
#define C_ 256
#define NPIX 4096      // 64*64
#define NP 1024        // 32*32

typedef __attribute__((ext_vector_type(8))) short bf16x8;
typedef __attribute__((ext_vector_type(4))) float f32x4;

#define GLL16(src, dst) __builtin_amdgcn_global_load_lds( \
    (__attribute__((address_space(1))) void*)(src), \
    (__attribute__((address_space(3))) void*)(dst), 16, 0, 0)

__device__ __forceinline__ unsigned short f2bf(float f) {
  unsigned int u = __float_as_uint(f);
  unsigned int r = (u + 0x7FFFu + ((u >> 16) & 1u)) >> 16;
  return (unsigned short)r;
}
__device__ __forceinline__ unsigned int pk2(unsigned short lo, unsigned short hi) {
  return (unsigned int)lo | ((unsigned int)hi << 16);
}

// ---------- reductions ----------
__device__ __forceinline__ float wave_reduce_sum(float v) {
#pragma unroll
  for (int off = 32; off > 0; off >>= 1) v += __shfl_down(v, off, 64);
  return v;
}
__device__ __forceinline__ float wave_reduce_max(float v) {
#pragma unroll
  for (int off = 32; off > 0; off >>= 1) v = fmaxf(v, __shfl_down(v, off, 64));
  return v;
}

// ---------- bilinear resize, align_corners=True, bit-exact f32 linspace ----------
__global__ __launch_bounds__(256) void k_resize(const float* __restrict__ in, float* __restrict__ out,
                                                int IH, int IW, int OH, int OW, int nElem) {
  int idx = blockIdx.x * 256 + threadIdx.x;
  if (idx >= nElem) return;
  int ox = idx % OW; int t = idx / OW; int oy = t % OH; int bc = t / OH;
  float dy = (float)(IH - 1) / (float)(OH - 1);
  float dx = (float)(IW - 1) / (float)(OW - 1);
  float yf = (float)oy * dy;
  float xf = (float)ox * dx;
  float y0f = floorf(yf), x0f = floorf(xf);
  int y0 = (int)y0f, x0 = (int)x0f;
  int y1 = min(y0 + 1, IH - 1), x1 = min(x0 + 1, IW - 1);
  float wy = yf - y0f, wx = xf - x0f;
  const float* p = in + (size_t)bc * IH * IW;
  float a = p[y0 * IW + x0], b = p[y0 * IW + x1];
  float c = p[y1 * IW + x0], d = p[y1 * IW + x1];
  float top = a * (1.0f - wx) + b * wx;
  float bot = c * (1.0f - wx) + d * wx;
  out[idx] = top * (1.0f - wy) + bot * wy;
}

// ---------- weight prep: Wc,Wm -> Wp1[kk 0..17][co][ci] bf16; Wf -> Wp2[kk 0..8][co][ci] ----------
__global__ __launch_bounds__(256) void k_wprep(const float* __restrict__ Wc, const float* __restrict__ Wm,
                                               const float* __restrict__ Wf,
                                               unsigned short* __restrict__ Wp1, unsigned short* __restrict__ Wp2) {
  int idx = blockIdx.x * 256 + threadIdx.x;
  if (idx >= 3 * 589824) return;
  int part = idx / 589824;            // 0=Wc 1=Wm 2=Wf
  int rem = idx % 589824;             // kk*65536 + co*256 + ci
  int kk = rem >> 16, co = (rem >> 8) & 255, ci = rem & 255;
  const float* W = (part == 0) ? Wc : (part == 1) ? Wm : Wf;
  unsigned short o = f2bf(W[(size_t)co * 2304 + ci * 9 + kk]);
  if (part == 0) Wp1[rem] = o;
  else if (part == 1) Wp1[589824 + rem] = o;
  else Wp2[rem] = o;
}

__global__ __launch_bounds__(256) void k_bias(const float* __restrict__ bc, const float* __restrict__ bm,
                                              float* __restrict__ bias1, float* __restrict__ zpg) {
  int i = threadIdx.x;
  bias1[i] = bc[i] + bm[i];
  for (int j = i; j < 2048; j += 256) zpg[j] = 0.f;
}

// ---------- A prep: A0 = bf16((fg+bg)*(1-m)), A1 = bf16((fg+bg)*m), layout [b][ci][pix] ----------
__global__ __launch_bounds__(256) void k_prepA(const float* __restrict__ fg, const float* __restrict__ bg,
                                               const float* __restrict__ m64,
                                               unsigned short* __restrict__ A0, unsigned short* __restrict__ A1) {
  int i = blockIdx.x * 256 + threadIdx.x;
  if (i >= (B_ * C_ * NPIX) / 4) return;
  int e = i * 4;
  int pix = e & (NPIX - 1);
  int b = e >> 20;                      // 256*4096 = 2^20
  float4 f = ((const float4*)fg)[i];
  float4 g = ((const float4*)bg)[i];
  float4 m = *(const float4*)&m64[(b << 12) + pix];
  float s0 = f.x + g.x, s1 = f.y + g.y, s2 = f.z + g.z, s3 = f.w + g.w;
  uint2 a0, a1;
  a0.x = pk2(f2bf(s0 * (1.f - m.x)), f2bf(s1 * (1.f - m.y)));
  a0.y = pk2(f2bf(s2 * (1.f - m.z)), f2bf(s3 * (1.f - m.w)));
  a1.x = pk2(f2bf(s0 * m.x), f2bf(s1 * m.y));
  a1.y = pk2(f2bf(s2 * m.z), f2bf(s3 * m.w));
  ((uint2*)A0)[i] = a0;
  ((uint2*)A1)[i] = a1;
}

// ---------- MFMA implicit-GEMM conv ----------
__device__ __forceinline__ int swz(int row, int slot) {
  return row * 32 + ((slot ^ (row & 3) ^ ((row >> 2) & 3)) << 3);   // ushort units
}

template <int NKK, bool OUT_BF16>
__global__ __launch_bounds__(256) void k_conv_mfma(const unsigned short* __restrict__ A0,
                                                   const unsigned short* __restrict__ A1,
                                                   const unsigned short* __restrict__ Wp,
                                                   const float* __restrict__ bias,
                                                   void* __restrict__ outp) {
  __shared__ __align__(16) unsigned short Alds[4096];   // [128 pix][32 ci] swizzled
  __shared__ __align__(16) unsigned short Blds[4096];   // [128 co ][32 ci] swizzled
  int bp = blockIdx.x, cot = blockIdx.y, b = blockIdx.z;
  int tid = threadIdx.x;
  int lane = tid & 63, wave = tid >> 6;
  int wm = wave >> 1, wn = wave & 1;
  f32x4 acc[4][4];
#pragma unroll
  for (int i = 0; i < 4; i++)
#pragma unroll
    for (int j = 0; j < 4; j++) acc[i][j] = (f32x4){0.f, 0.f, 0.f, 0.f};

  int sp = tid & 127;      // A: pixel-in-tile; B: co-in-tile
  int hg = tid >> 7;       // ci half (16 each)
  int pr = sp >> 6, pc = sp & 63;
  int y0 = bp * 2;

  for (int kk = 0; kk < NKK; ++kk) {
    int kw = (kk < 9) ? kk : kk - 9;
    int ky = kw / 3, kx = kw % 3;
    const unsigned short* Asrc = (NKK == 18 && kk >= 9) ? A1 : A0;
    int gy = y0 + pr + ky - 1, gx = pc + kx - 1;
    bool valid = (gy >= 0 && gy < 64 && gx >= 0 && gx < 64);
    const unsigned short* abase = Asrc + ((size_t)b * C_ * NPIX + gy * 64 + gx);
    const unsigned short* wbase = Wp + ((size_t)(kk * 256 + cot * 128 + sp) * 256 + hg * 16);

    for (int ci0 = 0; ci0 < 256; ci0 += 32) {
      __syncthreads();
      unsigned short av[16];
#pragma unroll
      for (int j = 0; j < 16; j++) {
        int ci = ci0 + hg * 16 + j;
        av[j] = valid ? abase[(size_t)ci * NPIX] : (unsigned short)0;
      }
      {
        uint4 w0 = {pk2(av[0], av[1]), pk2(av[2], av[3]), pk2(av[4], av[5]), pk2(av[6], av[7])};
        uint4 w1 = {pk2(av[8], av[9]), pk2(av[10], av[11]), pk2(av[12], av[13]), pk2(av[14], av[15])};
        *(uint4*)&Alds[swz(sp, hg * 2 + 0)] = w0;
        *(uint4*)&Alds[swz(sp, hg * 2 + 1)] = w1;
      }
      {
        uint4 b0 = *(const uint4*)(wbase + ci0);
        uint4 b1 = *(const uint4*)(wbase + ci0 + 8);
        *(uint4*)&Blds[swz(sp, hg * 2 + 0)] = b0;
        *(uint4*)&Blds[swz(sp, hg * 2 + 1)] = b1;
      }
      __syncthreads();
      int slot = lane >> 4;
      int mr = wm * 64 + (lane & 15);
      int nc = wn * 64 + (lane & 15);
      bf16x8 af[4], bfr[4];
#pragma unroll
      for (int i = 0; i < 4; i++) af[i] = *(const bf16x8*)&Alds[swz(mr + i * 16, slot)];
#pragma unroll
      for (int j = 0; j < 4; j++) bfr[j] = *(const bf16x8*)&Blds[swz(nc + j * 16, slot)];
#pragma unroll
      for (int i = 0; i < 4; i++)
#pragma unroll
        for (int j = 0; j < 4; j++)
          acc[i][j] = __builtin_amdgcn_mfma_f32_16x16x32_bf16(af[i], bfr[j], acc[i][j], 0, 0, 0);
    }
  }
  int co0 = cot * 128 + wn * 64 + (lane & 15);
  int px0 = bp * 128 + wm * 64 + ((lane >> 4) << 2);
#pragma unroll
  for (int j = 0; j < 4; j++) {
    int co = co0 + j * 16;
    float bs = bias[co];
#pragma unroll
    for (int i = 0; i < 4; i++) {
#pragma unroll
      for (int r = 0; r < 4; r++) {
        float v = acc[i][j][r] + bs;
        size_t oi = ((size_t)(b * C_ + co) * NPIX + px0 + i * 16 + r);
        if (OUT_BF16) ((unsigned short*)outp)[oi] = f2bf(v);
        else ((float*)outp)[oi] = v;
      }
    }
  }
}

// ---------- instance norm + swish ----------
__global__ __launch_bounds__(256) void k_innorm(float* __restrict__ x) {
  __shared__ float s4[4];
  int bc = blockIdx.x;
  float* p = x + (size_t)bc * NPIX;
  int tid = threadIdx.x;
  int lane = tid & 63, w = tid >> 6;
  float v[16];
  float s = 0.f;
#pragma unroll
  for (int i = 0; i < 16; i++) { v[i] = p[tid + i * 256]; s += v[i]; }
  s = wave_reduce_sum(s);
  if (lane == 0) s4[w] = s;
  __syncthreads();
  float mean = (s4[0] + s4[1] + s4[2] + s4[3]) * (1.0f / 4096.0f);
  __syncthreads();
  float s2 = 0.f;
#pragma unroll
  for (int i = 0; i < 16; i++) { float d = v[i] - mean; s2 += d * d; }
  s2 = wave_reduce_sum(s2);
  if (lane == 0) s4[w] = s2;
  __syncthreads();
  float var = (s4[0] + s4[1] + s4[2] + s4[3]) * (1.0f / 4096.0f);
  float inv = 1.0f / sqrtf(var + 1e-5f);
#pragma unroll
  for (int i = 0; i < 16; i++) {
    float xn = (v[i] - mean) * inv;
    float sg = 1.0f / (1.0f + expf(-xn));
    p[tid + i * 256] = xn * sg;
  }
}

// ---------- f32 -> bf16 copies ----------
__global__ __launch_bounds__(256) void k_f2bf4(const float4* __restrict__ in, uint2* __restrict__ outb, int n4) {
  int i = blockIdx.x * 256 + threadIdx.x;
  if (i >= n4) return;
  float4 v = in[i];
  uint2 o;
  o.x = pk2(f2bf(v.x), f2bf(v.y));
  o.y = pk2(f2bf(v.z), f2bf(v.w));
  outb[i] = o;
}

// ---------- per-pixel channel sum of squares of x_down ----------
__global__ __launch_bounds__(256) void k_sq32(const float* __restrict__ xd, float* __restrict__ sq) {
  int idx = blockIdx.x * 256 + threadIdx.x;
  if (idx >= B_ * NP) return;
  int pix = idx & 1023; int b = idx >> 10;
  const float* p = xd + (size_t)b * C_ * NP + pix;
  float s = 0.f;
  for (int c = 0; c < C_; c++) { float v = p[c * NP]; s += v * v; }
  sq[idx] = s;
}

// ---------- fq[q] = mm ? 1/max(norm,1e-4) : 0 ----------
__global__ __launch_bounds__(256) void k_normmm(const float* __restrict__ sq, const float* __restrict__ m32,
                                                float* __restrict__ fq) {
  int idx = blockIdx.x * 256 + threadIdx.x;
  if (idx >= B_ * NP) return;
  int q = idx & 1023, b = idx >> 10;
  int qi = q >> 5, qj = q & 31;
  float ns = 0.f, ms = 0.f;
#pragma unroll
  for (int k = 0; k < 3; k++)
#pragma unroll
    for (int l = 0; l < 3; l++) {
      int r = qi + k - 1, c = qj + l - 1;
      if (r >= 0 && r < 32 && c >= 0 && c < 32) {
        ns += sq[b * NP + r * 32 + c];
        ms += m32[b * NP + r * 32 + c];
      }
    }
  float f = (ms == 0.0f) ? (1.0f / fmaxf(sqrtf(ns), 1e-4f)) : 0.0f;
  fq[idx] = f;
}

// ---------- Gram MFMA ----------
__global__ __launch_bounds__(256) void k_gram_mfma(const unsigned short* __restrict__ xdb,
                                                   const float* __restrict__ fq,
                                                   float* __restrict__ sc) {
  __shared__ __align__(16) unsigned short Alds[4096];
  __shared__ __align__(16) unsigned short Blds[4096];
  int bp = blockIdx.x, bq = blockIdx.y, b = blockIdx.z;
  int tid = threadIdx.x;
  int lane = tid & 63, wave = tid >> 6;
  int wm = wave >> 1, wn = wave & 1;
  f32x4 acc[4][4];
#pragma unroll
  for (int i = 0; i < 4; i++)
#pragma unroll
    for (int j = 0; j < 4; j++) acc[i][j] = (f32x4){0.f, 0.f, 0.f, 0.f};

  int sp = tid & 127;
  int hg = tid >> 7;
  int pA = bp * 128 + sp, piA = pA >> 5, pjA = pA & 31;
  int pB = bq * 128 + sp, piB = pB >> 5, pjB = pB & 31;
  const unsigned short* xb = xdb + (size_t)b * C_ * NP;

  for (int kk = 0; kk < 9; ++kk) {
    int dy = kk / 3 - 1, dx = kk % 3 - 1;
    int gyA = piA + dy, gxA = pjA + dx;
    int gyB = piB + dy, gxB = pjB + dx;
    bool vA = (gyA >= 0 && gyA < 32 && gxA >= 0 && gxA < 32);
    bool vB = (gyB >= 0 && gyB < 32 && gxB >= 0 && gxB < 32);
    const unsigned short* baseA = xb + gyA * 32 + gxA;
    const unsigned short* baseB = xb + gyB * 32 + gxB;
    for (int ci0 = 0; ci0 < 256; ci0 += 32) {
      __syncthreads();
      unsigned short av[16], bv[16];
#pragma unroll
      for (int j = 0; j < 16; j++) {
        int ci = ci0 + hg * 16 + j;
        av[j] = vA ? baseA[(size_t)ci * NP] : (unsigned short)0;
        bv[j] = vB ? baseB[(size_t)ci * NP] : (unsigned short)0;
      }
      {
        uint4 w0 = {pk2(av[0], av[1]), pk2(av[2], av[3]), pk2(av[4], av[5]), pk2(av[6], av[7])};
        uint4 w1 = {pk2(av[8], av[9]), pk2(av[10], av[11]), pk2(av[12], av[13]), pk2(av[14], av[15])};
        *(uint4*)&Alds[swz(sp, hg * 2 + 0)] = w0;
        *(uint4*)&Alds[swz(sp, hg * 2 + 1)] = w1;
        uint4 u0 = {pk2(bv[0], bv[1]), pk2(bv[2], bv[3]), pk2(bv[4], bv[5]), pk2(bv[6], bv[7])};
        uint4 u1 = {pk2(bv[8], bv[9]), pk2(bv[10], bv[11]), pk2(bv[12], bv[13]), pk2(bv[14], bv[15])};
        *(uint4*)&Blds[swz(sp, hg * 2 + 0)] = u0;
        *(uint4*)&Blds[swz(sp, hg * 2 + 1)] = u1;
      }
      __syncthreads();
      int slot = lane >> 4;
      int mr = wm * 64 + (lane & 15);
      int nc = wn * 64 + (lane & 15);
      bf16x8 af[4], bfr[4];
#pragma unroll
      for (int i = 0; i < 4; i++) af[i] = *(const bf16x8*)&Alds[swz(mr + i * 16, slot)];
#pragma unroll
      for (int j = 0; j < 4; j++) bfr[j] = *(const bf16x8*)&Blds[swz(nc + j * 16, slot)];
#pragma unroll
      for (int i = 0; i < 4; i++)
#pragma unroll
        for (int j = 0; j < 4; j++)
          acc[i][j] = __builtin_amdgcn_mfma_f32_16x16x32_bf16(af[i], bfr[j], acc[i][j], 0, 0, 0);
    }
  }
  int q0 = bq * 128 + wn * 64 + (lane & 15);
  int p0 = bp * 128 + wm * 64 + ((lane >> 4) << 2);
#pragma unroll
  for (int j = 0; j < 4; j++) {
    int q = q0 + j * 16;
    float f = fq[b * NP + q];
#pragma unroll
    for (int i = 0; i < 4; i++)
#pragma unroll
      for (int r = 0; r < 4; r++)
        sc[((size_t)b * NP + (p0 + i * 16 + r)) * NP + q] = acc[i][j][r] * f;
  }
}

// ---------- softmax over q for each (b,p); emits att in bf16 ----------
__global__ __launch_bounds__(256) void k_softmax(const float* __restrict__ sc, const float* __restrict__ fq,
                                                 unsigned short* __restrict__ attb) {
  __shared__ float s4[4];
  int row = blockIdx.x;        // b*1024 + p
  int b = row >> 10;
  const float* r = sc + (size_t)row * NP;
  int tid = threadIdx.x;
  int lane = tid & 63, w = tid >> 6;
  float4 sv = *(const float4*)&r[tid * 4];
  float l0 = sv.x * 10.f, l1 = sv.y * 10.f, l2 = sv.z * 10.f, l3 = sv.w * 10.f;
  float mx = fmaxf(fmaxf(l0, l1), fmaxf(l2, l3));
  mx = wave_reduce_max(mx);
  if (lane == 0) s4[w] = mx;
  __syncthreads();
  float M = fmaxf(fmaxf(s4[0], s4[1]), fmaxf(s4[2], s4[3]));
  __syncthreads();
  float e0 = expf(l0 - M), e1 = expf(l1 - M), e2 = expf(l2 - M), e3 = expf(l3 - M);
  float s = e0 + e1 + e2 + e3;
  s = wave_reduce_sum(s);
  if (lane == 0) s4[w] = s;
  __syncthreads();
  float inv = 1.0f / (s4[0] + s4[1] + s4[2] + s4[3]);
  const float* fb = fq + b * NP + tid * 4;
  float m0 = fb[0] > 0.f ? 1.f : 0.f;
  float m1 = fb[1] > 0.f ? 1.f : 0.f;
  float m2 = fb[2] > 0.f ? 1.f : 0.f;
  float m3 = fb[3] > 0.f ? 1.f : 0.f;
  float a0 = fmaxf(e0 * inv * m0, 1e-8f);
  float a1 = fmaxf(e1 * inv * m1, 1e-8f);
  float a2 = fmaxf(e2 * inv * m2, 1e-8f);
  float a3 = fmaxf(e3 * inv * m3, 1e-8f);
  uint2 o;
  o.x = pk2(f2bf(a0), f2bf(a1));
  o.y = pk2(f2bf(a2), f2bf(a3));
  *(uint2*)&attb[(size_t)row * NP + tid * 4] = o;
}

// ---------- x -> parity-split pre-shifted bf16 copies P0/P1/P2 ----------
// P*[b][cy][cx][co][yh][32]: P0[s]=v[s], P1[s]=v[s-1], P2[s]=v[s+1] (zero halo)
__global__ __launch_bounds__(256) void k_xprep(const float* __restrict__ x,
                                               unsigned short* __restrict__ P0,
                                               unsigned short* __restrict__ P1,
                                               unsigned short* __restrict__ P2) {
  int idx = blockIdx.x * 256 + threadIdx.x;   // 2^20 total
  int xh8 = idx & 3;
  int yh = (idx >> 2) & 31;
  int co = (idx >> 7) & 255;
  int pc = (idx >> 15) & 3;
  int b  = idx >> 17;
  int cy = pc >> 1, cx = pc & 1;
  // thread covers half-res x in [8*xh8, 8*xh8+8) -> full-res x in [16*xh8, 16*xh8+16)
  const float* row = x + ((size_t)(b * 256 + co) * 64 + (2 * yh + cy)) * 64 + 16 * xh8;
  float4 f0 = *(const float4*)(row);
  float4 f1 = *(const float4*)(row + 4);
  float4 f2 = *(const float4*)(row + 8);
  float4 f3 = *(const float4*)(row + 12);
  unsigned short v0 = f2bf(cx ? f0.y : f0.x), v1 = f2bf(cx ? f0.w : f0.z);
  unsigned short v2 = f2bf(cx ? f1.y : f1.x), v3 = f2bf(cx ? f1.w : f1.z);
  unsigned short v4 = f2bf(cx ? f2.y : f2.x), v5 = f2bf(cx ? f2.w : f2.z);
  unsigned short v6 = f2bf(cx ? f3.y : f3.x), v7 = f2bf(cx ? f3.w : f3.z);
  int prev = __shfl_up((int)v7, 1, 64);
  int next = __shfl_down((int)v0, 1, 64);
  unsigned short pv = (xh8 == 0) ? (unsigned short)0 : (unsigned short)prev;
  unsigned short nx = (xh8 == 3) ? (unsigned short)0 : (unsigned short)next;
  size_t base = ((size_t)((b * 4 + pc) * 256 + co) * 32 + yh) * 32 + 8 * xh8;
  uint4 w0 = {pk2(v0, v1), pk2(v2, v3), pk2(v4, v5), pk2(v6, v7)};
  *(uint4*)&P0[base] = w0;
  uint4 w1 = {pk2(pv, v0), pk2(v1, v2), pk2(v3, v4), pk2(v5, v6)};
  *(uint4*)&P1[base] = w1;
  uint4 w2 = {pk2(v1, v2), pk2(v3, v4), pk2(v5, v6), pk2(v7, nx)};
  *(uint4*)&P2[base] = w2;
}

// ---------- PV class-GEMM, 2-phase counted-vmcnt pipeline + global_load_lds ----------
__global__ __launch_bounds__(256, 2) void k_pv(const unsigned short* __restrict__ attb,
                                               const unsigned short* __restrict__ P0,
                                               const unsigned short* __restrict__ P1,
                                               const unsigned short* __restrict__ P2,
                                               const unsigned short* __restrict__ zp,
                                               const float* __restrict__ xbuf,
                                               const float* __restrict__ m64,
                                               float* __restrict__ out) {
  __shared__ __align__(16) unsigned short AB[2][8192];  // [buf][A 4096 | B 4096]
  int wg = blockIdx.x + blockIdx.y * 8 + blockIdx.z * 16;
  int nid = (wg & 7) * 64 + (wg >> 3);      // chunked XCD swizzle (512 = 8*64, bijective)
  int bn = nid & 7, bm = (nid >> 3) & 1, z = nid >> 4;
  int b = z >> 2, cls = z & 3, cy = cls >> 1, cx = cls & 1;
  int tid = threadIdx.x, lane = tid & 63, w3 = tid >> 6;
  int wm = w3 >> 1, wn = w3 & 1;

  int dy1 = cy ? -1 : 1;
  int pio1 = cy ? 1 : -1;
  int pjo1 = cx ? 1 : -1;
  const unsigned short* Pdx = cx ? P1 : P2;   // dx=+1 -> P2, dx=-1 -> P1

  // per-thread staging constants: row = w3*32 + k*16 + (lane>>2)
  int rA0 = w3 * 32 + (lane >> 2);
  int rA1 = rA0 + 16;
  int ds0 = (lane & 3) ^ (rA0 & 3) ^ ((rA0 >> 2) & 3);
  int ds1 = (lane & 3) ^ (rA1 & 3) ^ ((rA1 >> 2) & 3);
  int offA0 = ((z * 256 + bm * 128 + rA0) << 10) + ds0 * 8;
  int offA1 = ((z * 256 + bm * 128 + rA1) << 10) + ds1 * 8;

  const unsigned short* attB = attb + ((size_t)b << 20);
  int o0 = bn * 128 + rA0, o1 = bn * 128 + rA1;
  int oy0 = o0 >> 5, ox0 = o0 & 31, oy1 = o1 >> 5, ox1 = o1 & 31;
#define BPTR(oyv, oxv, dsv, tyv, txv) ({                                        \
    int pi = (oyv) + ((tyv) ? pio1 : 0);                                        \
    int pj = (oxv) + ((txv) ? pjo1 : 0);                                        \
    (pi >= 0 && pi < 32 && pj >= 0 && pj < 32)                                  \
        ? attB + (((pi << 5) + pj) << 10) + (dsv) * 8 : zp; })
  const unsigned short* b0t0 = BPTR(oy0, ox0, ds0, 0, 0);
  const unsigned short* b0t1 = BPTR(oy0, ox0, ds0, 0, 1);
  const unsigned short* b0t2 = BPTR(oy0, ox0, ds0, 1, 0);
  const unsigned short* b0t3 = BPTR(oy0, ox0, ds0, 1, 1);
  const unsigned short* b1t0 = BPTR(oy1, ox1, ds1, 0, 0);
  const unsigned short* b1t1 = BPTR(oy1, ox1, ds1, 0, 1);
  const unsigned short* b1t2 = BPTR(oy1, ox1, ds1, 1, 0);
  const unsigned short* b1t3 = BPTR(oy1, ox1, ds1, 1, 1);
#undef BPTR

  f32x4 acc[4][4];
#pragma unroll
  for (int i = 0; i < 4; i++)
#pragma unroll
    for (int j = 0; j < 4; j++) acc[i][j] = (f32x4){0.f, 0.f, 0.f, 0.f};

  int dA0 = w3 * 1024, dA1 = w3 * 1024 + 512;
  int dB0 = 4096 + w3 * 1024, dB1 = 4096 + w3 * 1024 + 512;

#define STAGE(c2, buf) {                                                        \
    int t2 = (c2) >> 5, qi = (c2) & 31;                                         \
    int q32 = qi * 32;                                                          \
    const unsigned short* Ab = (t2 & 1) ? Pdx : P0;                             \
    int dyo = (t2 >> 1) ? dy1 * 32 : 0;                                         \
    bool vA = (t2 < 2) || ((dy1 > 0) ? (qi < 31) : (qi > 0));                   \
    if (!vA) Ab = zp;                                                           \
    int oA0 = vA ? offA0 + dyo + q32 : 0;                                       \
    int oA1 = vA ? offA1 + dyo + q32 : 0;                                       \
    unsigned short* lb = &AB[buf][0];                                           \
    GLL16(Ab + oA0, lb + dA0);                                                  \
    GLL16(Ab + oA1, lb + dA1);                                                  \
    const unsigned short* sB0 = (t2 == 0 ? b0t0 : t2 == 1 ? b0t1 : t2 == 2 ? b0t2 : b0t3) + q32; \
    const unsigned short* sB1 = (t2 == 0 ? b1t0 : t2 == 1 ? b1t1 : t2 == 2 ? b1t2 : b1t3) + q32; \
    GLL16(sB0, lb + dB0);                                                       \
    GLL16(sB1, lb + dB1);                                                       \
  }

  STAGE(0, 0);
  for (int c = 0; c < 128; ++c) {
    asm volatile("" ::: "memory");
    __builtin_amdgcn_s_barrier();          // all waves done reading buf[(c+1)&1]
    asm volatile("" ::: "memory");
    if (c < 127) {
      STAGE(c + 1, (c + 1) & 1);
      asm volatile("s_waitcnt vmcnt(4)" ::: "memory");   // chunk c's 4 loads landed
    } else {
      asm volatile("s_waitcnt vmcnt(0)" ::: "memory");
    }
    __builtin_amdgcn_s_barrier();          // buf[c&1] fully staged by all waves
    asm volatile("" ::: "memory");
    const unsigned short* Al = &AB[c & 1][0];
    const unsigned short* Bl = &AB[c & 1][4096];
    int slot = lane >> 4;
    int mr = wm * 64 + (lane & 15), ncc = wn * 64 + (lane & 15);
    bf16x8 af[4], bfr[4];
#pragma unroll
    for (int i = 0; i < 4; i++) af[i] = *(const bf16x8*)&Al[swz(mr + i * 16, slot)];
#pragma unroll
    for (int j = 0; j < 4; j++) bfr[j] = *(const bf16x8*)&Bl[swz(ncc + j * 16, slot)];
#pragma unroll
    for (int i = 0; i < 4; i++)
#pragma unroll
      for (int j = 0; j < 4; j++)
        acc[i][j] = __builtin_amdgcn_mfma_f32_16x16x32_bf16(af[i], bfr[j], acc[i][j], 0, 0, 0);
  }
#undef STAGE

  // epilogue: m = co (row), n = o (col); blend with x
  int co0 = bm * 128 + wm * 64 + ((lane >> 4) << 2);
  int oo0 = bn * 128 + wn * 64 + (lane & 15);
#pragma unroll
  for (int j = 0; j < 4; j++) {
    int o = oo0 + j * 16;
    int oy = ((o >> 5) << 1) + cy, ox = ((o & 31) << 1) + cx;
    int opix = oy * 64 + ox;
    float msk = m64[b * NPIX + opix];
    float s = 0.25f * msk, t1m = 1.0f - msk;
#pragma unroll
    for (int i = 0; i < 4; i++) {
#pragma unroll
      for (int r = 0; r < 4; r++) {
        int co = co0 + i * 16 + r;
        size_t xi = (size_t)(b * C_ + co) * NPIX + opix;
        out[xi] = acc[i][j][r] * s + xbuf[xi] * t1m;
      }
    }
  }
}

extern "C" void kernel_launch(void* const* d_in, const int* in_sizes, int n_in,
                              void* d_out, int out_size, void* d_ws, size_t ws_size,
                              hipStream_t stream) {
  const float* bg   = (const float*)d_in[0];
  const float* fg   = (const float*)d_in[1];
  const float* mask = (const float*)d_in[2];
  const float* Wc   = (const float*)d_in[3];
  const float* bc   = (const float*)d_in[4];
  const float* Wm   = (const float*)d_in[5];
  const float* bm   = (const float*)d_in[6];
  const float* Wf   = (const float*)d_in[7];
  const float* bf   = (const float*)d_in[8];
  float* out = (float*)d_out;
  float* w = (float*)d_ws;

  // workspace (float offsets), total 25,231,360 floats = 100.9 MB
  float* mask64 = w;                          // 32768
  float* mask32 = w + 32768;                  // 8192
  float* sq32   = w + 40960;                  // 8192
  float* fq     = w + 49152;                  // 8192
  float* bias1  = w + 57344;                  // 256
  float* zpage  = w + 57600;                  // 2048 zeros (8 KB)
  // region1 [65536, 8454144): A0b/A1b (convs) -> sc f32 (gram/softmax) -> P0+P1 (pv)
  unsigned short* A0b = (unsigned short*)(w + 65536);
  unsigned short* A1b = (unsigned short*)(w + 65536 + 4194304);
  float* sc = w + 65536;
  unsigned short* P0u = (unsigned short*)(w + 65536);            // 8,388,608 ushorts
  unsigned short* P1u = (unsigned short*)(w + 4259840);          // 8,388,608 ushorts
  // region2 [8454144, 12648448): tbuf bf16 -> xd f32 + xdb bf16 -> attb bf16
  unsigned short* tbuf = (unsigned short*)(w + 8454144);
  float* xd = w + 8454144;                    // 2097152 floats
  unsigned short* xdb = (unsigned short*)(w + 10551296);
  unsigned short* attb = (unsigned short*)(w + 8454144);
  float* xbuf = w + 12648448;                 // 8388608
  unsigned short* Wp1 = (unsigned short*)(w + 21037056);         // convs only
  unsigned short* Wp2 = (unsigned short*)(w + 21626880);
  unsigned short* P2u = (unsigned short*)(w + 21037056);         // after convs

  hipLaunchKernelGGL(k_resize, dim3(128), dim3(256), 0, stream, mask, mask64, 256, 256, 64, 64, 32768);
  hipLaunchKernelGGL(k_wprep, dim3(6912), dim3(256), 0, stream, Wc, Wm, Wf, Wp1, Wp2);
  hipLaunchKernelGGL(k_bias, dim3(1), dim3(256), 0, stream, bc, bm, bias1, zpage);
  hipLaunchKernelGGL(k_prepA, dim3(8192), dim3(256), 0, stream, fg, bg, mask64, A0b, A1b);
  hipLaunchKernelGGL((k_conv_mfma<18, true>), dim3(32, 2, 8), dim3(256), 0, stream, A0b, A1b, Wp1, bias1, (void*)tbuf);
  hipLaunchKernelGGL((k_conv_mfma<9, false>), dim3(32, 2, 8), dim3(256), 0, stream, tbuf, tbuf, Wp2, bf, (void*)xbuf);
  hipLaunchKernelGGL(k_innorm, dim3(B_ * C_), dim3(256), 0, stream, xbuf);
  hipLaunchKernelGGL(k_resize, dim3(8192), dim3(256), 0, stream, xbuf, xd, 64, 64, 32, 32, B_ * C_ * NP);
  hipLaunchKernelGGL(k_resize, dim3(32), dim3(256), 0, stream, mask64, mask32, 64, 64, 32, 32, B_ * NP);
  hipLaunchKernelGGL(k_f2bf4, dim3(2048), dim3(256), 0, stream, (const float4*)xd, (uint2*)xdb, (B_ * C_ * NP) / 4);
  hipLaunchKernelGGL(k_sq32, dim3(32), dim3(256), 0, stream, xd, sq32);
  hipLaunchKernelGGL(k_normmm, dim3(32), dim3(256), 0, stream, sq32, mask32, fq);
  hipLaunchKernelGGL(k_gram_mfma, dim3(8, 8, 8), dim3(256), 0, stream, xdb, fq, sc);
  hipLaunchKernelGGL(k_softmax, dim3(B_ * NP), dim3(256), 0, stream, sc, fq, attb);
  // sc dead -> build P0/P1 (region1) and P2 (weight region) from xbuf
  hipLaunchKernelGGL(k_xprep, dim3(4096), dim3(256), 0, stream, xbuf, P0u, P1u, P2u);
  // PV class-GEMM + blend -> out
  hipLaunchKernelGGL(k_pv, dim3(8, 2, 32), dim3(256), 0, stream, attb, P0u, P1u, P2u,
                     (const unsigned short*)zpage, xbuf, mask64, out);
}

// Round 7
// 356.085 us; speedup vs baseline: 27.4928x; 1.5182x over previous
//
#include <hip/hip_runtime.h>
#include <math.h>

#define B_ 8
#define C_ 256
#define NPIX 4096      // 64*64
#define NP 1024        // 32*32

typedef __attribute__((ext_vector_type(8))) short bf16x8;
typedef __attribute__((ext_vector_type(4))) float f32x4;

#define GLL16(src, dst) __builtin_amdgcn_global_load_lds( \
    (__attribute__((address_space(1))) void*)(src), \
    (__attribute__((address_space(3))) void*)(dst), 16, 0, 0)

__device__ __forceinline__ unsigned short f2bf(float f) {
  unsigned int u = __float_as_uint(f);
  unsigned int r = (u + 0x7FFFu + ((u >> 16) & 1u)) >> 16;
  return (unsigned short)r;
}
__device__ __forceinline__ unsigned int pk2(unsigned short lo, unsigned short hi) {
  return (unsigned int)lo | ((unsigned int)hi << 16);
}

// ---------- reductions ----------
__device__ __forceinline__ float wave_reduce_sum(float v) {
#pragma unroll
  for (int off = 32; off > 0; off >>= 1) v += __shfl_down(v, off, 64);
  return v;
}
__device__ __forceinline__ float wave_reduce_max(float v) {
#pragma unroll
  for (int off = 32; off > 0; off >>= 1) v = fmaxf(v, __shfl_down(v, off, 64));
  return v;
}

// ---------- bilinear resize, align_corners=True, bit-exact f32 linspace ----------
__global__ __launch_bounds__(256) void k_resize(const float* __restrict__ in, float* __restrict__ out,
                                                int IH, int IW, int OH, int OW, int nElem) {
  int idx = blockIdx.x * 256 + threadIdx.x;
  if (idx >= nElem) return;
  int ox = idx % OW; int t = idx / OW; int oy = t % OH; int bc = t / OH;
  float dy = (float)(IH - 1) / (float)(OH - 1);
  float dx = (float)(IW - 1) / (float)(OW - 1);
  float yf = (float)oy * dy;
  float xf = (float)ox * dx;
  float y0f = floorf(yf), x0f = floorf(xf);
  int y0 = (int)y0f, x0 = (int)x0f;
  int y1 = min(y0 + 1, IH - 1), x1 = min(x0 + 1, IW - 1);
  float wy = yf - y0f, wx = xf - x0f;
  const float* p = in + (size_t)bc * IH * IW;
  float a = p[y0 * IW + x0], b = p[y0 * IW + x1];
  float c = p[y1 * IW + x0], d = p[y1 * IW + x1];
  float top = a * (1.0f - wx) + b * wx;
  float bot = c * (1.0f - wx) + d * wx;
  out[idx] = top * (1.0f - wy) + bot * wy;
}

// ---------- weight prep: Wc,Wm -> Wp1[kk 0..17][co][ci] bf16; Wf -> Wp2[kk 0..8][co][ci] ----------
__global__ __launch_bounds__(256) void k_wprep(const float* __restrict__ Wc, const float* __restrict__ Wm,
                                               const float* __restrict__ Wf,
                                               unsigned short* __restrict__ Wp1, unsigned short* __restrict__ Wp2) {
  int idx = blockIdx.x * 256 + threadIdx.x;
  if (idx >= 3 * 589824) return;
  int part = idx / 589824;            // 0=Wc 1=Wm 2=Wf
  int rem = idx % 589824;             // kk*65536 + co*256 + ci
  int kk = rem >> 16, co = (rem >> 8) & 255, ci = rem & 255;
  const float* W = (part == 0) ? Wc : (part == 1) ? Wm : Wf;
  unsigned short o = f2bf(W[(size_t)co * 2304 + ci * 9 + kk]);
  if (part == 0) Wp1[rem] = o;
  else if (part == 1) Wp1[589824 + rem] = o;
  else Wp2[rem] = o;
}

__global__ __launch_bounds__(256) void k_bias(const float* __restrict__ bc, const float* __restrict__ bm,
                                              float* __restrict__ bias1, float* __restrict__ zpg) {
  int i = threadIdx.x;
  bias1[i] = bc[i] + bm[i];
  for (int j = i; j < 2048; j += 256) zpg[j] = 0.f;
}

// ---------- A prep TRANSPOSED: A0t/A1t [b][pix][ci] bf16 via LDS tile transpose ----------
__global__ __launch_bounds__(256) void k_prepAT(const float* __restrict__ fg, const float* __restrict__ bg,
                                                const float* __restrict__ m64,
                                                unsigned short* __restrict__ A0t, unsigned short* __restrict__ A1t) {
  __shared__ unsigned short T0[64][66];
  __shared__ unsigned short T1[64][66];
  int pt = blockIdx.x, ct = blockIdx.y, b = blockIdx.z;   // (64, 4, 8)
  int pix0 = pt << 6, ci0 = ct << 6;
  int tid = threadIdx.x;
  {
    int r = tid >> 2, c4 = (tid & 3) << 4;
    size_t ib = (((size_t)(b * 256 + ci0 + r)) << 12) + pix0 + c4;
    const float* fb = fg + ib;
    const float* gb = bg + ib;
    const float* mb = m64 + (((size_t)b) << 12) + pix0 + c4;
#pragma unroll
    for (int k = 0; k < 16; k += 4) {
      float4 f = *(const float4*)(fb + k);
      float4 g = *(const float4*)(gb + k);
      float4 m = *(const float4*)(mb + k);
      float s0 = f.x + g.x, s1 = f.y + g.y, s2 = f.z + g.z, s3 = f.w + g.w;
      T0[r][c4 + k + 0] = f2bf(s0 * (1.f - m.x));
      T0[r][c4 + k + 1] = f2bf(s1 * (1.f - m.y));
      T0[r][c4 + k + 2] = f2bf(s2 * (1.f - m.z));
      T0[r][c4 + k + 3] = f2bf(s3 * (1.f - m.w));
      T1[r][c4 + k + 0] = f2bf(s0 * m.x);
      T1[r][c4 + k + 1] = f2bf(s1 * m.y);
      T1[r][c4 + k + 2] = f2bf(s2 * m.z);
      T1[r][c4 + k + 3] = f2bf(s3 * m.w);
    }
  }
  __syncthreads();
  {
    int pr = tid >> 2, cc = (tid & 3) << 4;
    unsigned int o0[8], o1[8];
#pragma unroll
    for (int k = 0; k < 8; k++) {
      o0[k] = pk2(T0[cc + 2 * k][pr], T0[cc + 2 * k + 1][pr]);
      o1[k] = pk2(T1[cc + 2 * k][pr], T1[cc + 2 * k + 1][pr]);
    }
    size_t ob = ((((size_t)b << 12) + pix0 + pr) << 8) + ci0 + cc;
    *(uint4*)&A0t[ob] = *(uint4*)&o0[0];
    *(uint4*)&A0t[ob + 8] = *(uint4*)&o0[4];
    *(uint4*)&A1t[ob] = *(uint4*)&o1[0];
    *(uint4*)&A1t[ob + 8] = *(uint4*)&o1[4];
  }
}

// ---------- LDS fragment swizzle ----------
__device__ __forceinline__ int swz(int row, int slot) {
  return row * 32 + ((slot ^ (row & 3) ^ ((row >> 2) & 3)) << 3);   // ushort units
}

// ---------- conv implicit-GEMM, 2-phase GLL16 pipeline. A transposed [b][pix][ci]. ----------
// conv1 (NKK=18): out bf16 transposed [b][pix][co]; conv2 (NKK=9): out f32 [b][co][pix].
template <int NKK, bool OUT_TRANS_BF16>
__global__ __launch_bounds__(256, 2) void k_conv2ph(const unsigned short* __restrict__ A0t,
                                                    const unsigned short* __restrict__ A1t,
                                                    const unsigned short* __restrict__ Wp,
                                                    const float* __restrict__ bias,
                                                    const unsigned short* __restrict__ zp,
                                                    void* __restrict__ outp) {
  __shared__ __align__(16) unsigned short AB[2][8192];   // [buf][A 4096 | B 4096]
  int wgl = blockIdx.x + 32 * (blockIdx.y + 2 * blockIdx.z);     // grid (32,2,8)
  int nid = (wgl & 7) * 64 + (wgl >> 3);                         // XCD-chunk: one b per XCD
  int bp = nid & 31, cot = (nid >> 5) & 1, b = nid >> 6;
  int tid = threadIdx.x, lane = tid & 63, w3 = tid >> 6;
  int wm = w3 >> 1, wn = w3 & 1;

  int rA = w3 * 32 + (lane >> 2), rA1 = rA + 16;
  int ds0 = (lane & 3) ^ (rA & 3) ^ ((rA >> 2) & 3);
  int ds1 = (lane & 3) ^ (rA1 & 3) ^ ((rA1 >> 2) & 3);
  int y_0 = bp * 2 + (rA >> 6), x_0 = rA & 63;
  int y_1 = bp * 2 + (rA1 >> 6), x_1 = rA1 & 63;
  int co_0 = cot * 128 + rA, co_1 = cot * 128 + rA1;

  f32x4 acc[4][4];
#pragma unroll
  for (int i = 0; i < 4; i++)
#pragma unroll
    for (int j = 0; j < 4; j++) acc[i][j] = (f32x4){0.f, 0.f, 0.f, 0.f};

  const unsigned short *pA0, *pA1, *pB0, *pB1;

#define UPDATE(kkv) {                                                           \
    int kk_ = (kkv);                                                            \
    int kw_ = (NKK == 18 && kk_ >= 9) ? kk_ - 9 : kk_;                          \
    const unsigned short* Asrc_ = (NKK == 18 && kk_ >= 9) ? A1t : A0t;          \
    int ky_ = kw_ / 3 - 1, kx_ = kw_ % 3 - 1;                                   \
    int yy0_ = y_0 + ky_, xx0_ = x_0 + kx_;                                     \
    int yy1_ = y_1 + ky_, xx1_ = x_1 + kx_;                                     \
    pA0 = ((unsigned)yy0_ < 64u && (unsigned)xx0_ < 64u)                        \
        ? Asrc_ + ((((size_t)(b << 6) + yy0_) << 6) + xx0_) * 256 + ds0 * 8     \
        : zp + ds0 * 8;                                                         \
    pA1 = ((unsigned)yy1_ < 64u && (unsigned)xx1_ < 64u)                        \
        ? Asrc_ + ((((size_t)(b << 6) + yy1_) << 6) + xx1_) * 256 + ds1 * 8     \
        : zp + ds1 * 8;                                                         \
    pB0 = Wp + ((size_t)kk_ << 16) + co_0 * 256 + ds0 * 8;                      \
    pB1 = Wp + ((size_t)kk_ << 16) + co_1 * 256 + ds1 * 8;                      \
  }
#define STAGE(c2, buf) {                                                        \
    int ci0_ = ((c2) & 7) << 5;                                                 \
    unsigned short* lb_ = &AB[buf][0];                                          \
    GLL16(pA0 + ci0_, lb_ + w3 * 1024);                                         \
    GLL16(pA1 + ci0_, lb_ + w3 * 1024 + 512);                                   \
    GLL16(pB0 + ci0_, lb_ + 4096 + w3 * 1024);                                  \
    GLL16(pB1 + ci0_, lb_ + 4096 + w3 * 1024 + 512);                            \
  }

  const int NCH = NKK * 8;
  UPDATE(0);
  STAGE(0, 0);
  for (int c = 0; c < NCH; ++c) {
    asm volatile("" ::: "memory");
    __builtin_amdgcn_s_barrier();
    asm volatile("" ::: "memory");
    if (c < NCH - 1) {
      int cn = c + 1;
      if ((cn & 7) == 0) UPDATE(cn >> 3);
      STAGE(cn, cn & 1);
      asm volatile("s_waitcnt vmcnt(4)" ::: "memory");
    } else {
      asm volatile("s_waitcnt vmcnt(0)" ::: "memory");
    }
    __builtin_amdgcn_s_barrier();
    asm volatile("" ::: "memory");
    const unsigned short* Al = &AB[c & 1][0];
    const unsigned short* Bl = &AB[c & 1][4096];
    int slot = lane >> 4;
    int mr = wm * 64 + (lane & 15), ncc = wn * 64 + (lane & 15);
    bf16x8 af[4], bfr[4];
#pragma unroll
    for (int i = 0; i < 4; i++) af[i] = *(const bf16x8*)&Al[swz(mr + i * 16, slot)];
#pragma unroll
    for (int j = 0; j < 4; j++) bfr[j] = *(const bf16x8*)&Bl[swz(ncc + j * 16, slot)];
#pragma unroll
    for (int i = 0; i < 4; i++)
#pragma unroll
      for (int j = 0; j < 4; j++)
        acc[i][j] = __builtin_amdgcn_mfma_f32_16x16x32_bf16(af[i], bfr[j], acc[i][j], 0, 0, 0);
  }
#undef STAGE
#undef UPDATE

  // epilogue: m = pix (A rows), n = co (B rows)
  int px0 = bp * 128 + wm * 64 + ((lane >> 4) << 2);
  int co0 = cot * 128 + wn * 64 + (lane & 15);
#pragma unroll
  for (int j = 0; j < 4; j++) {
    int co = co0 + j * 16;
    float bs = bias[co];
#pragma unroll
    for (int i = 0; i < 4; i++) {
#pragma unroll
      for (int r = 0; r < 4; r++) {
        float v = acc[i][j][r] + bs;
        int pix = px0 + i * 16 + r;
        if (OUT_TRANS_BF16)
          ((unsigned short*)outp)[((((size_t)b << 12) + pix) << 8) + co] = f2bf(v);
        else
          ((float*)outp)[((((size_t)b << 8) + co) << 12) + pix] = v;
      }
    }
  }
}

// ---------- instance norm + swish ----------
__global__ __launch_bounds__(256) void k_innorm(float* __restrict__ x) {
  __shared__ float s4[4];
  int bc = blockIdx.x;
  float* p = x + (size_t)bc * NPIX;
  int tid = threadIdx.x;
  int lane = tid & 63, w = tid >> 6;
  float v[16];
  float s = 0.f;
#pragma unroll
  for (int i = 0; i < 16; i++) { v[i] = p[tid + i * 256]; s += v[i]; }
  s = wave_reduce_sum(s);
  if (lane == 0) s4[w] = s;
  __syncthreads();
  float mean = (s4[0] + s4[1] + s4[2] + s4[3]) * (1.0f / 4096.0f);
  __syncthreads();
  float s2 = 0.f;
#pragma unroll
  for (int i = 0; i < 16; i++) { float d = v[i] - mean; s2 += d * d; }
  s2 = wave_reduce_sum(s2);
  if (lane == 0) s4[w] = s2;
  __syncthreads();
  float var = (s4[0] + s4[1] + s4[2] + s4[3]) * (1.0f / 4096.0f);
  float inv = 1.0f / sqrtf(var + 1e-5f);
#pragma unroll
  for (int i = 0; i < 16; i++) {
    float xn = (v[i] - mean) * inv;
    float sg = 1.0f / (1.0f + expf(-xn));
    p[tid + i * 256] = xn * sg;
  }
}

// ---------- xd f32 [b][ci][qpix] -> xdt bf16 [b][qpix][ci] (LDS tile transpose) ----------
__global__ __launch_bounds__(256) void k_trans_xd(const float* __restrict__ xd,
                                                  unsigned short* __restrict__ xdt) {
  __shared__ unsigned short T[64][66];
  int qt = blockIdx.x, ct = blockIdx.y, b = blockIdx.z;    // (16, 4, 8)
  int q0 = qt << 6, ci0 = ct << 6;
  int tid = threadIdx.x;
  {
    int r = tid >> 2, c4 = (tid & 3) << 4;
    const float* xb = xd + (((size_t)(b * 256 + ci0 + r)) << 10) + q0 + c4;
#pragma unroll
    for (int k = 0; k < 16; k += 4) {
      float4 f = *(const float4*)(xb + k);
      T[r][c4 + k + 0] = f2bf(f.x);
      T[r][c4 + k + 1] = f2bf(f.y);
      T[r][c4 + k + 2] = f2bf(f.z);
      T[r][c4 + k + 3] = f2bf(f.w);
    }
  }
  __syncthreads();
  {
    int qr = tid >> 2, cc = (tid & 3) << 4;
    unsigned int o[8];
#pragma unroll
    for (int k = 0; k < 8; k++) o[k] = pk2(T[cc + 2 * k][qr], T[cc + 2 * k + 1][qr]);
    size_t ob = ((((size_t)b << 10) + q0 + qr) << 8) + ci0 + cc;
    *(uint4*)&xdt[ob] = *(uint4*)&o[0];
    *(uint4*)&xdt[ob + 8] = *(uint4*)&o[4];
  }
}

// ---------- per-pixel channel sum of squares of x_down ----------
__global__ __launch_bounds__(256) void k_sq32(const float* __restrict__ xd, float* __restrict__ sq) {
  int idx = blockIdx.x * 256 + threadIdx.x;
  if (idx >= B_ * NP) return;
  int pix = idx & 1023; int b = idx >> 10;
  const float* p = xd + (size_t)b * C_ * NP + pix;
  float s = 0.f;
  for (int c = 0; c < C_; c++) { float v = p[c * NP]; s += v * v; }
  sq[idx] = s;
}

// ---------- fq[q] = mm ? 1/max(norm,1e-4) : 0 ----------
__global__ __launch_bounds__(256) void k_normmm(const float* __restrict__ sq, const float* __restrict__ m32,
                                                float* __restrict__ fq) {
  int idx = blockIdx.x * 256 + threadIdx.x;
  if (idx >= B_ * NP) return;
  int q = idx & 1023, b = idx >> 10;
  int qi = q >> 5, qj = q & 31;
  float ns = 0.f, ms = 0.f;
#pragma unroll
  for (int k = 0; k < 3; k++)
#pragma unroll
    for (int l = 0; l < 3; l++) {
      int r = qi + k - 1, c = qj + l - 1;
      if (r >= 0 && r < 32 && c >= 0 && c < 32) {
        ns += sq[b * NP + r * 32 + c];
        ms += m32[b * NP + r * 32 + c];
      }
    }
  float f = (ms == 0.0f) ? (1.0f / fmaxf(sqrtf(ns), 1e-4f)) : 0.0f;
  fq[idx] = f;
}

// ---------- Gram, 2-phase GLL16 pipeline from xdt [b][qpix][ci] ----------
__global__ __launch_bounds__(256, 2) void k_gram2ph(const unsigned short* __restrict__ xdt,
                                                    const float* __restrict__ fq,
                                                    const unsigned short* __restrict__ zp,
                                                    float* __restrict__ sc) {
  __shared__ __align__(16) unsigned short AB[2][8192];
  int wgl = blockIdx.x + 8 * (blockIdx.y + 8 * blockIdx.z);      // grid (8,8,8)
  int nid = (wgl & 7) * 64 + (wgl >> 3);
  int bp = nid & 7, bq = (nid >> 3) & 7, b = nid >> 6;
  int tid = threadIdx.x, lane = tid & 63, w3 = tid >> 6;
  int wm = w3 >> 1, wn = w3 & 1;

  int rA = w3 * 32 + (lane >> 2), rA1 = rA + 16;
  int ds0 = (lane & 3) ^ (rA & 3) ^ ((rA >> 2) & 3);
  int ds1 = (lane & 3) ^ (rA1 & 3) ^ ((rA1 >> 2) & 3);
  int pA0r = bp * 128 + rA, pA1r = bp * 128 + rA1;
  int pB0r = bq * 128 + rA, pB1r = bq * 128 + rA1;
  int piA0 = pA0r >> 5, pjA0 = pA0r & 31, piA1 = pA1r >> 5, pjA1 = pA1r & 31;
  int piB0 = pB0r >> 5, pjB0 = pB0r & 31, piB1 = pB1r >> 5, pjB1 = pB1r & 31;
  const unsigned short* xb = xdt + (((size_t)b) << 18);

  f32x4 acc[4][4];
#pragma unroll
  for (int i = 0; i < 4; i++)
#pragma unroll
    for (int j = 0; j < 4; j++) acc[i][j] = (f32x4){0.f, 0.f, 0.f, 0.f};

  const unsigned short *pA0, *pA1, *pB0, *pB1;

#define GUPDATE(kkv) {                                                          \
    int kk_ = (kkv);                                                            \
    int dy_ = kk_ / 3 - 1, dx_ = kk_ % 3 - 1;                                   \
    int ya0 = piA0 + dy_, xa0 = pjA0 + dx_;                                     \
    int ya1 = piA1 + dy_, xa1 = pjA1 + dx_;                                     \
    int yb0 = piB0 + dy_, xb0 = pjB0 + dx_;                                     \
    int yb1 = piB1 + dy_, xb1 = pjB1 + dx_;                                     \
    pA0 = ((unsigned)ya0 < 32u && (unsigned)xa0 < 32u)                          \
        ? xb + ((((size_t)ya0 << 5) + xa0) << 8) + ds0 * 8 : zp + ds0 * 8;      \
    pA1 = ((unsigned)ya1 < 32u && (unsigned)xa1 < 32u)                          \
        ? xb + ((((size_t)ya1 << 5) + xa1) << 8) + ds1 * 8 : zp + ds1 * 8;      \
    pB0 = ((unsigned)yb0 < 32u && (unsigned)xb0 < 32u)                          \
        ? xb + ((((size_t)yb0 << 5) + xb0) << 8) + ds0 * 8 : zp + ds0 * 8;      \
    pB1 = ((unsigned)yb1 < 32u && (unsigned)xb1 < 32u)                          \
        ? xb + ((((size_t)yb1 << 5) + xb1) << 8) + ds1 * 8 : zp + ds1 * 8;      \
  }
#define GSTAGE(c2, buf) {                                                       \
    int ci0_ = ((c2) & 7) << 5;                                                 \
    unsigned short* lb_ = &AB[buf][0];                                          \
    GLL16(pA0 + ci0_, lb_ + w3 * 1024);                                         \
    GLL16(pA1 + ci0_, lb_ + w3 * 1024 + 512);                                   \
    GLL16(pB0 + ci0_, lb_ + 4096 + w3 * 1024);                                  \
    GLL16(pB1 + ci0_, lb_ + 4096 + w3 * 1024 + 512);                            \
  }

  GUPDATE(0);
  GSTAGE(0, 0);
  for (int c = 0; c < 72; ++c) {
    asm volatile("" ::: "memory");
    __builtin_amdgcn_s_barrier();
    asm volatile("" ::: "memory");
    if (c < 71) {
      int cn = c + 1;
      if ((cn & 7) == 0) GUPDATE(cn >> 3);
      GSTAGE(cn, cn & 1);
      asm volatile("s_waitcnt vmcnt(4)" ::: "memory");
    } else {
      asm volatile("s_waitcnt vmcnt(0)" ::: "memory");
    }
    __builtin_amdgcn_s_barrier();
    asm volatile("" ::: "memory");
    const unsigned short* Al = &AB[c & 1][0];
    const unsigned short* Bl = &AB[c & 1][4096];
    int slot = lane >> 4;
    int mr = wm * 64 + (lane & 15), ncc = wn * 64 + (lane & 15);
    bf16x8 af[4], bfr[4];
#pragma unroll
    for (int i = 0; i < 4; i++) af[i] = *(const bf16x8*)&Al[swz(mr + i * 16, slot)];
#pragma unroll
    for (int j = 0; j < 4; j++) bfr[j] = *(const bf16x8*)&Bl[swz(ncc + j * 16, slot)];
#pragma unroll
    for (int i = 0; i < 4; i++)
#pragma unroll
      for (int j = 0; j < 4; j++)
        acc[i][j] = __builtin_amdgcn_mfma_f32_16x16x32_bf16(af[i], bfr[j], acc[i][j], 0, 0, 0);
  }
#undef GSTAGE
#undef GUPDATE

  int q0 = bq * 128 + wn * 64 + (lane & 15);
  int p0 = bp * 128 + wm * 64 + ((lane >> 4) << 2);
#pragma unroll
  for (int j = 0; j < 4; j++) {
    int q = q0 + j * 16;
    float f = fq[(b << 10) + q];
#pragma unroll
    for (int i = 0; i < 4; i++)
#pragma unroll
      for (int r = 0; r < 4; r++)
        sc[((size_t)(b << 10) + (p0 + i * 16 + r)) * NP + q] = acc[i][j][r] * f;
  }
}

// ---------- softmax over q for each (b,p); emits att in bf16 ----------
__global__ __launch_bounds__(256) void k_softmax(const float* __restrict__ sc, const float* __restrict__ fq,
                                                 unsigned short* __restrict__ attb) {
  __shared__ float s4[4];
  int row = blockIdx.x;        // b*1024 + p
  int b = row >> 10;
  const float* r = sc + (size_t)row * NP;
  int tid = threadIdx.x;
  int lane = tid & 63, w = tid >> 6;
  float4 sv = *(const float4*)&r[tid * 4];
  float l0 = sv.x * 10.f, l1 = sv.y * 10.f, l2 = sv.z * 10.f, l3 = sv.w * 10.f;
  float mx = fmaxf(fmaxf(l0, l1), fmaxf(l2, l3));
  mx = wave_reduce_max(mx);
  if (lane == 0) s4[w] = mx;
  __syncthreads();
  float M = fmaxf(fmaxf(s4[0], s4[1]), fmaxf(s4[2], s4[3]));
  __syncthreads();
  float e0 = expf(l0 - M), e1 = expf(l1 - M), e2 = expf(l2 - M), e3 = expf(l3 - M);
  float s = e0 + e1 + e2 + e3;
  s = wave_reduce_sum(s);
  if (lane == 0) s4[w] = s;
  __syncthreads();
  float inv = 1.0f / (s4[0] + s4[1] + s4[2] + s4[3]);
  const float* fb = fq + b * NP + tid * 4;
  float m0 = fb[0] > 0.f ? 1.f : 0.f;
  float m1 = fb[1] > 0.f ? 1.f : 0.f;
  float m2 = fb[2] > 0.f ? 1.f : 0.f;
  float m3 = fb[3] > 0.f ? 1.f : 0.f;
  float a0 = fmaxf(e0 * inv * m0, 1e-8f);
  float a1 = fmaxf(e1 * inv * m1, 1e-8f);
  float a2 = fmaxf(e2 * inv * m2, 1e-8f);
  float a3 = fmaxf(e3 * inv * m3, 1e-8f);
  uint2 o;
  o.x = pk2(f2bf(a0), f2bf(a1));
  o.y = pk2(f2bf(a2), f2bf(a3));
  *(uint2*)&attb[(size_t)row * NP + tid * 4] = o;
}

// ---------- x -> parity-split pre-shifted bf16 copies P0/P1/P2 ----------
__global__ __launch_bounds__(256) void k_xprep(const float* __restrict__ x,
                                               unsigned short* __restrict__ P0,
                                               unsigned short* __restrict__ P1,
                                               unsigned short* __restrict__ P2) {
  int idx = blockIdx.x * 256 + threadIdx.x;   // 2^20 total
  int xh8 = idx & 3;
  int yh = (idx >> 2) & 31;
  int co = (idx >> 7) & 255;
  int pc = (idx >> 15) & 3;
  int b  = idx >> 17;
  int cy = pc >> 1, cx = pc & 1;
  const float* row = x + ((size_t)(b * 256 + co) * 64 + (2 * yh + cy)) * 64 + 16 * xh8;
  float4 f0 = *(const float4*)(row);
  float4 f1 = *(const float4*)(row + 4);
  float4 f2 = *(const float4*)(row + 8);
  float4 f3 = *(const float4*)(row + 12);
  unsigned short v0 = f2bf(cx ? f0.y : f0.x), v1 = f2bf(cx ? f0.w : f0.z);
  unsigned short v2 = f2bf(cx ? f1.y : f1.x), v3 = f2bf(cx ? f1.w : f1.z);
  unsigned short v4 = f2bf(cx ? f2.y : f2.x), v5 = f2bf(cx ? f2.w : f2.z);
  unsigned short v6 = f2bf(cx ? f3.y : f3.x), v7 = f2bf(cx ? f3.w : f3.z);
  int prev = __shfl_up((int)v7, 1, 64);
  int next = __shfl_down((int)v0, 1, 64);
  unsigned short pv = (xh8 == 0) ? (unsigned short)0 : (unsigned short)prev;
  unsigned short nx = (xh8 == 3) ? (unsigned short)0 : (unsigned short)next;
  size_t base = ((size_t)((b * 4 + pc) * 256 + co) * 32 + yh) * 32 + 8 * xh8;
  uint4 w0 = {pk2(v0, v1), pk2(v2, v3), pk2(v4, v5), pk2(v6, v7)};
  *(uint4*)&P0[base] = w0;
  uint4 w1 = {pk2(pv, v0), pk2(v1, v2), pk2(v3, v4), pk2(v5, v6)};
  *(uint4*)&P1[base] = w1;
  uint4 w2 = {pk2(v1, v2), pk2(v3, v4), pk2(v5, v6), pk2(v7, nx)};
  *(uint4*)&P2[base] = w2;
}

// ---------- PV class-GEMM, 2-phase counted-vmcnt pipeline + global_load_lds ----------
__global__ __launch_bounds__(256, 2) void k_pv(const unsigned short* __restrict__ attb,
                                               const unsigned short* __restrict__ P0,
                                               const unsigned short* __restrict__ P1,
                                               const unsigned short* __restrict__ P2,
                                               const unsigned short* __restrict__ zp,
                                               const float* __restrict__ xbuf,
                                               const float* __restrict__ m64,
                                               float* __restrict__ out) {
  __shared__ __align__(16) unsigned short AB[2][8192];
  int wg = blockIdx.x + blockIdx.y * 8 + blockIdx.z * 16;
  int nid = (wg & 7) * 64 + (wg >> 3);
  int bn = nid & 7, bm = (nid >> 3) & 1, z = nid >> 4;
  int b = z >> 2, cls = z & 3, cy = cls >> 1, cx = cls & 1;
  int tid = threadIdx.x, lane = tid & 63, w3 = tid >> 6;
  int wm = w3 >> 1, wn = w3 & 1;

  int dy1 = cy ? -1 : 1;
  int pio1 = cy ? 1 : -1;
  int pjo1 = cx ? 1 : -1;
  const unsigned short* Pdx = cx ? P1 : P2;

  int rA0 = w3 * 32 + (lane >> 2);
  int rA1 = rA0 + 16;
  int ds0 = (lane & 3) ^ (rA0 & 3) ^ ((rA0 >> 2) & 3);
  int ds1 = (lane & 3) ^ (rA1 & 3) ^ ((rA1 >> 2) & 3);
  int offA0 = ((z * 256 + bm * 128 + rA0) << 10) + ds0 * 8;
  int offA1 = ((z * 256 + bm * 128 + rA1) << 10) + ds1 * 8;

  const unsigned short* attB = attb + ((size_t)b << 20);
  int o0 = bn * 128 + rA0, o1 = bn * 128 + rA1;
  int oy0 = o0 >> 5, ox0 = o0 & 31, oy1 = o1 >> 5, ox1 = o1 & 31;
#define BPTR(oyv, oxv, dsv, tyv, txv) ({                                        \
    int pi = (oyv) + ((tyv) ? pio1 : 0);                                        \
    int pj = (oxv) + ((txv) ? pjo1 : 0);                                        \
    (pi >= 0 && pi < 32 && pj >= 0 && pj < 32)                                  \
        ? attB + (((pi << 5) + pj) << 10) + (dsv) * 8 : zp; })
  const unsigned short* b0t0 = BPTR(oy0, ox0, ds0, 0, 0);
  const unsigned short* b0t1 = BPTR(oy0, ox0, ds0, 0, 1);
  const unsigned short* b0t2 = BPTR(oy0, ox0, ds0, 1, 0);
  const unsigned short* b0t3 = BPTR(oy0, ox0, ds0, 1, 1);
  const unsigned short* b1t0 = BPTR(oy1, ox1, ds1, 0, 0);
  const unsigned short* b1t1 = BPTR(oy1, ox1, ds1, 0, 1);
  const unsigned short* b1t2 = BPTR(oy1, ox1, ds1, 1, 0);
  const unsigned short* b1t3 = BPTR(oy1, ox1, ds1, 1, 1);
#undef BPTR

  f32x4 acc[4][4];
#pragma unroll
  for (int i = 0; i < 4; i++)
#pragma unroll
    for (int j = 0; j < 4; j++) acc[i][j] = (f32x4){0.f, 0.f, 0.f, 0.f};

  int dA0 = w3 * 1024, dA1 = w3 * 1024 + 512;
  int dB0 = 4096 + w3 * 1024, dB1 = 4096 + w3 * 1024 + 512;

#define PSTAGE(c2, buf) {                                                       \
    int t2 = (c2) >> 5, qi = (c2) & 31;                                         \
    int q32 = qi * 32;                                                          \
    const unsigned short* Ab = (t2 & 1) ? Pdx : P0;                             \
    int dyo = (t2 >> 1) ? dy1 * 32 : 0;                                         \
    bool vA = (t2 < 2) || ((dy1 > 0) ? (qi < 31) : (qi > 0));                   \
    if (!vA) Ab = zp;                                                           \
    int oA0 = vA ? offA0 + dyo + q32 : 0;                                       \
    int oA1 = vA ? offA1 + dyo + q32 : 0;                                       \
    unsigned short* lb = &AB[buf][0];                                           \
    GLL16(Ab + oA0, lb + dA0);                                                  \
    GLL16(Ab + oA1, lb + dA1);                                                  \
    const unsigned short* sB0 = (t2 == 0 ? b0t0 : t2 == 1 ? b0t1 : t2 == 2 ? b0t2 : b0t3) + q32; \
    const unsigned short* sB1 = (t2 == 0 ? b1t0 : t2 == 1 ? b1t1 : t2 == 2 ? b1t2 : b1t3) + q32; \
    GLL16(sB0, lb + dB0);                                                       \
    GLL16(sB1, lb + dB1);                                                       \
  }

  PSTAGE(0, 0);
  for (int c = 0; c < 128; ++c) {
    asm volatile("" ::: "memory");
    __builtin_amdgcn_s_barrier();
    asm volatile("" ::: "memory");
    if (c < 127) {
      PSTAGE(c + 1, (c + 1) & 1);
      asm volatile("s_waitcnt vmcnt(4)" ::: "memory");
    } else {
      asm volatile("s_waitcnt vmcnt(0)" ::: "memory");
    }
    __builtin_amdgcn_s_barrier();
    asm volatile("" ::: "memory");
    const unsigned short* Al = &AB[c & 1][0];
    const unsigned short* Bl = &AB[c & 1][4096];
    int slot = lane >> 4;
    int mr = wm * 64 + (lane & 15), ncc = wn * 64 + (lane & 15);
    bf16x8 af[4], bfr[4];
#pragma unroll
    for (int i = 0; i < 4; i++) af[i] = *(const bf16x8*)&Al[swz(mr + i * 16, slot)];
#pragma unroll
    for (int j = 0; j < 4; j++) bfr[j] = *(const bf16x8*)&Bl[swz(ncc + j * 16, slot)];
#pragma unroll
    for (int i = 0; i < 4; i++)
#pragma unroll
      for (int j = 0; j < 4; j++)
        acc[i][j] = __builtin_amdgcn_mfma_f32_16x16x32_bf16(af[i], bfr[j], acc[i][j], 0, 0, 0);
  }
#undef PSTAGE

  int co0 = bm * 128 + wm * 64 + ((lane >> 4) << 2);
  int oo0 = bn * 128 + wn * 64 + (lane & 15);
#pragma unroll
  for (int j = 0; j < 4; j++) {
    int o = oo0 + j * 16;
    int oy = ((o >> 5) << 1) + cy, ox = ((o & 31) << 1) + cx;
    int opix = oy * 64 + ox;
    float msk = m64[b * NPIX + opix];
    float s = 0.25f * msk, t1m = 1.0f - msk;
#pragma unroll
    for (int i = 0; i < 4; i++) {
#pragma unroll
      for (int r = 0; r < 4; r++) {
        int co = co0 + i * 16 + r;
        size_t xi = (size_t)(b * C_ + co) * NPIX + opix;
        out[xi] = acc[i][j][r] * s + xbuf[xi] * t1m;
      }
    }
  }
}

extern "C" void kernel_launch(void* const* d_in, const int* in_sizes, int n_in,
                              void* d_out, int out_size, void* d_ws, size_t ws_size,
                              hipStream_t stream) {
  const float* bg   = (const float*)d_in[0];
  const float* fg   = (const float*)d_in[1];
  const float* mask = (const float*)d_in[2];
  const float* Wc   = (const float*)d_in[3];
  const float* bc   = (const float*)d_in[4];
  const float* Wm   = (const float*)d_in[5];
  const float* bm   = (const float*)d_in[6];
  const float* Wf   = (const float*)d_in[7];
  const float* bf   = (const float*)d_in[8];
  float* out = (float*)d_out;
  float* w = (float*)d_ws;

  // workspace (float offsets), total 25,231,360 floats = 100.9 MB
  float* mask64 = w;                          // 32768
  float* mask32 = w + 32768;                  // 8192
  float* sq32   = w + 40960;                  // 8192
  float* fq     = w + 49152;                  // 8192
  float* bias1  = w + 57344;                  // 256
  float* zpage  = w + 57600;                  // 2048 zeros (8 KB)
  // region1 [65536, 8454144): A0t/A1t (convs) -> sc f32 (gram/softmax) -> P0+P1 (pv)
  unsigned short* A0t = (unsigned short*)(w + 65536);            // [b][pix][ci]
  unsigned short* A1t = (unsigned short*)(w + 65536 + 4194304);
  float* sc = w + 65536;
  unsigned short* P0u = (unsigned short*)(w + 65536);
  unsigned short* P1u = (unsigned short*)(w + 4259840);
  // region2 [8454144, 12648448): tbuf_t bf16 -> xd f32 + xdt bf16 -> attb bf16
  unsigned short* tbuf_t = (unsigned short*)(w + 8454144);       // [b][pix][co]
  float* xd = w + 8454144;                    // 2097152 floats [b][ci][qpix]
  unsigned short* xdt = (unsigned short*)(w + 10551296);         // [b][qpix][ci]
  unsigned short* attb = (unsigned short*)(w + 8454144);
  float* xbuf = w + 12648448;                 // 8388608 [b][co][pix]
  unsigned short* Wp1 = (unsigned short*)(w + 21037056);
  unsigned short* Wp2 = (unsigned short*)(w + 21626880);
  unsigned short* P2u = (unsigned short*)(w + 21037056);         // after convs

  const unsigned short* zp = (const unsigned short*)zpage;

  hipLaunchKernelGGL(k_resize, dim3(128), dim3(256), 0, stream, mask, mask64, 256, 256, 64, 64, 32768);
  hipLaunchKernelGGL(k_wprep, dim3(6912), dim3(256), 0, stream, Wc, Wm, Wf, Wp1, Wp2);
  hipLaunchKernelGGL(k_bias, dim3(1), dim3(256), 0, stream, bc, bm, bias1, zpage);
  hipLaunchKernelGGL(k_prepAT, dim3(64, 4, 8), dim3(256), 0, stream, fg, bg, mask64, A0t, A1t);
  // conv1 (dual masked conv, K=4608) -> tbuf_t bf16 [pix][co]
  hipLaunchKernelGGL((k_conv2ph<18, true>), dim3(32, 2, 8), dim3(256), 0, stream,
                     A0t, A1t, Wp1, bias1, zp, (void*)tbuf_t);
  // conv2 (K=2304) -> xbuf f32 [co][pix]
  hipLaunchKernelGGL((k_conv2ph<9, false>), dim3(32, 2, 8), dim3(256), 0, stream,
                     tbuf_t, tbuf_t, Wp2, bf, zp, (void*)xbuf);
  hipLaunchKernelGGL(k_innorm, dim3(B_ * C_), dim3(256), 0, stream, xbuf);
  hipLaunchKernelGGL(k_resize, dim3(8192), dim3(256), 0, stream, xbuf, xd, 64, 64, 32, 32, B_ * C_ * NP);
  hipLaunchKernelGGL(k_resize, dim3(32), dim3(256), 0, stream, mask64, mask32, 64, 64, 32, 32, B_ * NP);
  hipLaunchKernelGGL(k_trans_xd, dim3(16, 4, 8), dim3(256), 0, stream, xd, xdt);
  hipLaunchKernelGGL(k_sq32, dim3(32), dim3(256), 0, stream, xd, sq32);
  hipLaunchKernelGGL(k_normmm, dim3(32), dim3(256), 0, stream, sq32, mask32, fq);
  hipLaunchKernelGGL(k_gram2ph, dim3(8, 8, 8), dim3(256), 0, stream, xdt, fq, zp, sc);
  hipLaunchKernelGGL(k_softmax, dim3(B_ * NP), dim3(256), 0, stream, sc, fq, attb);
  hipLaunchKernelGGL(k_xprep, dim3(4096), dim3(256), 0, stream, xbuf, P0u, P1u, P2u);
  hipLaunchKernelGGL(k_pv, dim3(8, 2, 32), dim3(256), 0, stream, attb, P0u, P1u, P2u,
                     zp, xbuf, mask64, out);
}

// Round 8
// 338.275 us; speedup vs baseline: 28.9403x; 1.0526x over previous
//
#include <hip/hip_runtime.h>
#include <math.h>

#define B_ 8
#define C_ 256
#define NPIX 4096      // 64*64
#define NP 1024        // 32*32

typedef __attribute__((ext_vector_type(8))) short bf16x8;
typedef __attribute__((ext_vector_type(4))) float f32x4;

#define GLL16(src, dst) __builtin_amdgcn_global_load_lds( \
    (__attribute__((address_space(1))) void*)(src), \
    (__attribute__((address_space(3))) void*)(dst), 16, 0, 0)

__device__ __forceinline__ unsigned short f2bf(float f) {
  unsigned int u = __float_as_uint(f);
  unsigned int r = (u + 0x7FFFu + ((u >> 16) & 1u)) >> 16;
  return (unsigned short)r;
}
__device__ __forceinline__ unsigned int pk2(unsigned short lo, unsigned short hi) {
  return (unsigned int)lo | ((unsigned int)hi << 16);
}

// ---------- reductions ----------
__device__ __forceinline__ float wave_reduce_sum(float v) {
#pragma unroll
  for (int off = 32; off > 0; off >>= 1) v += __shfl_down(v, off, 64);
  return v;
}
__device__ __forceinline__ float wave_reduce_max(float v) {
#pragma unroll
  for (int off = 32; off > 0; off >>= 1) v = fmaxf(v, __shfl_down(v, off, 64));
  return v;
}

// ---------- bilinear resize, align_corners=True (used only for mask 256->64) ----------
__global__ __launch_bounds__(256) void k_resize(const float* __restrict__ in, float* __restrict__ out,
                                                int IH, int IW, int OH, int OW, int nElem) {
  int idx = blockIdx.x * 256 + threadIdx.x;
  if (idx >= nElem) return;
  int ox = idx % OW; int t = idx / OW; int oy = t % OH; int bc = t / OH;
  float dy = (float)(IH - 1) / (float)(OH - 1);
  float dx = (float)(IW - 1) / (float)(OW - 1);
  float yf = (float)oy * dy;
  float xf = (float)ox * dx;
  float y0f = floorf(yf), x0f = floorf(xf);
  int y0 = (int)y0f, x0 = (int)x0f;
  int y1 = min(y0 + 1, IH - 1), x1 = min(x0 + 1, IW - 1);
  float wy = yf - y0f, wx = xf - x0f;
  const float* p = in + (size_t)bc * IH * IW;
  float a = p[y0 * IW + x0], b = p[y0 * IW + x1];
  float c = p[y1 * IW + x0], d = p[y1 * IW + x1];
  float top = a * (1.0f - wx) + b * wx;
  float bot = c * (1.0f - wx) + d * wx;
  out[idx] = top * (1.0f - wy) + bot * wy;
}

// ---------- weight prep: Wc,Wm -> Wp1[kk 0..17][co][ci] bf16; Wf -> Wp2[kk 0..8][co][ci] ----------
__global__ __launch_bounds__(256) void k_wprep(const float* __restrict__ Wc, const float* __restrict__ Wm,
                                               const float* __restrict__ Wf,
                                               unsigned short* __restrict__ Wp1, unsigned short* __restrict__ Wp2) {
  int idx = blockIdx.x * 256 + threadIdx.x;
  if (idx >= 3 * 589824) return;
  int part = idx / 589824;            // 0=Wc 1=Wm 2=Wf
  int rem = idx % 589824;             // kk*65536 + co*256 + ci
  int kk = rem >> 16, co = (rem >> 8) & 255, ci = rem & 255;
  const float* W = (part == 0) ? Wc : (part == 1) ? Wm : Wf;
  unsigned short o = f2bf(W[(size_t)co * 2304 + ci * 9 + kk]);
  if (part == 0) Wp1[rem] = o;
  else if (part == 1) Wp1[589824 + rem] = o;
  else Wp2[rem] = o;
}

__global__ __launch_bounds__(256) void k_bias(const float* __restrict__ bc, const float* __restrict__ bm,
                                              float* __restrict__ bias1, float* __restrict__ zpg) {
  int i = threadIdx.x;
  bias1[i] = bc[i] + bm[i];
  for (int j = i; j < 2048; j += 256) zpg[j] = 0.f;
}

// ---------- A prep TRANSPOSED: A0t/A1t [b][pix][ci] bf16 via LDS tile transpose ----------
__global__ __launch_bounds__(256) void k_prepAT(const float* __restrict__ fg, const float* __restrict__ bg,
                                                const float* __restrict__ m64,
                                                unsigned short* __restrict__ A0t, unsigned short* __restrict__ A1t) {
  __shared__ unsigned short T0[64][66];
  __shared__ unsigned short T1[64][66];
  int pt = blockIdx.x, ct = blockIdx.y, b = blockIdx.z;   // (64, 4, 8)
  int pix0 = pt << 6, ci0 = ct << 6;
  int tid = threadIdx.x;
  {
    int r = tid >> 2, c4 = (tid & 3) << 4;
    size_t ib = (((size_t)(b * 256 + ci0 + r)) << 12) + pix0 + c4;
    const float* fb = fg + ib;
    const float* gb = bg + ib;
    const float* mb = m64 + (((size_t)b) << 12) + pix0 + c4;
#pragma unroll
    for (int k = 0; k < 16; k += 4) {
      float4 f = *(const float4*)(fb + k);
      float4 g = *(const float4*)(gb + k);
      float4 m = *(const float4*)(mb + k);
      float s0 = f.x + g.x, s1 = f.y + g.y, s2 = f.z + g.z, s3 = f.w + g.w;
      T0[r][c4 + k + 0] = f2bf(s0 * (1.f - m.x));
      T0[r][c4 + k + 1] = f2bf(s1 * (1.f - m.y));
      T0[r][c4 + k + 2] = f2bf(s2 * (1.f - m.z));
      T0[r][c4 + k + 3] = f2bf(s3 * (1.f - m.w));
      T1[r][c4 + k + 0] = f2bf(s0 * m.x);
      T1[r][c4 + k + 1] = f2bf(s1 * m.y);
      T1[r][c4 + k + 2] = f2bf(s2 * m.z);
      T1[r][c4 + k + 3] = f2bf(s3 * m.w);
    }
  }
  __syncthreads();
  {
    int pr = tid >> 2, cc = (tid & 3) << 4;
    unsigned int o0[8], o1[8];
#pragma unroll
    for (int k = 0; k < 8; k++) {
      o0[k] = pk2(T0[cc + 2 * k][pr], T0[cc + 2 * k + 1][pr]);
      o1[k] = pk2(T1[cc + 2 * k][pr], T1[cc + 2 * k + 1][pr]);
    }
    size_t ob = ((((size_t)b << 12) + pix0 + pr) << 8) + ci0 + cc;
    *(uint4*)&A0t[ob] = *(uint4*)&o0[0];
    *(uint4*)&A0t[ob + 8] = *(uint4*)&o0[4];
    *(uint4*)&A1t[ob] = *(uint4*)&o1[0];
    *(uint4*)&A1t[ob + 8] = *(uint4*)&o1[4];
  }
}

// ---------- LDS fragment swizzle ----------
__device__ __forceinline__ int swz(int row, int slot) {
  return row * 32 + ((slot ^ (row & 3) ^ ((row >> 2) & 3)) << 3);   // ushort units
}

// ---------- conv implicit-GEMM, 2-phase GLL16 pipeline, BK=64. A transposed [b][pix][ci]. ----------
// conv1 (NKK=18): out bf16 transposed [b][pix][co]; conv2 (NKK=9): out f32 [b][co][pix].
template <int NKK, bool OUT_TRANS_BF16>
__global__ __launch_bounds__(256, 2) void k_conv2ph(const unsigned short* __restrict__ A0t,
                                                    const unsigned short* __restrict__ A1t,
                                                    const unsigned short* __restrict__ Wp,
                                                    const float* __restrict__ bias,
                                                    const unsigned short* __restrict__ zp,
                                                    void* __restrict__ outp) {
  __shared__ __align__(16) unsigned short AB[2][16384];  // [buf][A_k0|A_k1|B_k0|B_k1] 8KB each
  int wgl = blockIdx.x + 32 * (blockIdx.y + 2 * blockIdx.z);     // grid (32,2,8)
  int nid = (wgl & 7) * 64 + (wgl >> 3);                         // XCD-chunk: one b per XCD
  int bp = nid & 31, cot = (nid >> 5) & 1, b = nid >> 6;
  int tid = threadIdx.x, lane = tid & 63, w3 = tid >> 6;
  int wm = w3 >> 1, wn = w3 & 1;

  int rA = w3 * 32 + (lane >> 2), rA1 = rA + 16;
  int ds0 = (lane & 3) ^ (rA & 3) ^ ((rA >> 2) & 3);
  int ds1 = (lane & 3) ^ (rA1 & 3) ^ ((rA1 >> 2) & 3);
  int y_0 = bp * 2 + (rA >> 6), x_0 = rA & 63;
  int y_1 = bp * 2 + (rA1 >> 6), x_1 = rA1 & 63;
  int co_0 = cot * 128 + rA, co_1 = cot * 128 + rA1;

  f32x4 acc[4][4];
#pragma unroll
  for (int i = 0; i < 4; i++)
#pragma unroll
    for (int j = 0; j < 4; j++) acc[i][j] = (f32x4){0.f, 0.f, 0.f, 0.f};

  const unsigned short *pA0, *pA1, *pB0, *pB1;

#define UPDATE(kkv) {                                                           \
    int kk_ = (kkv);                                                            \
    int kw_ = (NKK == 18 && kk_ >= 9) ? kk_ - 9 : kk_;                          \
    const unsigned short* Asrc_ = (NKK == 18 && kk_ >= 9) ? A1t : A0t;          \
    int ky_ = kw_ / 3 - 1, kx_ = kw_ % 3 - 1;                                   \
    int yy0_ = y_0 + ky_, xx0_ = x_0 + kx_;                                     \
    int yy1_ = y_1 + ky_, xx1_ = x_1 + kx_;                                     \
    pA0 = ((unsigned)yy0_ < 64u && (unsigned)xx0_ < 64u)                        \
        ? Asrc_ + ((((size_t)(b << 6) + yy0_) << 6) + xx0_) * 256 + ds0 * 8     \
        : zp + ds0 * 8;                                                         \
    pA1 = ((unsigned)yy1_ < 64u && (unsigned)xx1_ < 64u)                        \
        ? Asrc_ + ((((size_t)(b << 6) + yy1_) << 6) + xx1_) * 256 + ds1 * 8     \
        : zp + ds1 * 8;                                                         \
    pB0 = Wp + ((size_t)kk_ << 16) + co_0 * 256 + ds0 * 8;                      \
    pB1 = Wp + ((size_t)kk_ << 16) + co_1 * 256 + ds1 * 8;                      \
  }
#define STAGE(c2, buf) {                                                        \
    int ci0_ = ((c2) & 3) << 6;                                                 \
    unsigned short* lb_ = &AB[buf][0];                                          \
    GLL16(pA0 + ci0_,      lb_ + w3 * 1024);                                    \
    GLL16(pA1 + ci0_,      lb_ + w3 * 1024 + 512);                              \
    GLL16(pA0 + ci0_ + 32, lb_ + 4096 + w3 * 1024);                             \
    GLL16(pA1 + ci0_ + 32, lb_ + 4096 + w3 * 1024 + 512);                       \
    GLL16(pB0 + ci0_,      lb_ + 8192 + w3 * 1024);                             \
    GLL16(pB1 + ci0_,      lb_ + 8192 + w3 * 1024 + 512);                       \
    GLL16(pB0 + ci0_ + 32, lb_ + 12288 + w3 * 1024);                            \
    GLL16(pB1 + ci0_ + 32, lb_ + 12288 + w3 * 1024 + 512);                      \
  }

  const int NCH = NKK * 4;
  UPDATE(0);
  STAGE(0, 0);
  for (int c = 0; c < NCH; ++c) {
    asm volatile("" ::: "memory");
    __builtin_amdgcn_s_barrier();
    asm volatile("" ::: "memory");
    if (c < NCH - 1) {
      int cn = c + 1;
      if ((cn & 3) == 0) UPDATE(cn >> 2);
      STAGE(cn, cn & 1);
      asm volatile("s_waitcnt vmcnt(8)" ::: "memory");
    } else {
      asm volatile("s_waitcnt vmcnt(0)" ::: "memory");
    }
    __builtin_amdgcn_s_barrier();
    asm volatile("" ::: "memory");
    int slot = lane >> 4;
    int mr = wm * 64 + (lane & 15), ncc = wn * 64 + (lane & 15);
#pragma unroll
    for (int ks = 0; ks < 2; ++ks) {
      const unsigned short* Al = &AB[c & 1][ks << 12];
      const unsigned short* Bl = &AB[c & 1][8192 + (ks << 12)];
      bf16x8 af[4], bfr[4];
#pragma unroll
      for (int i = 0; i < 4; i++) af[i] = *(const bf16x8*)&Al[swz(mr + i * 16, slot)];
#pragma unroll
      for (int j = 0; j < 4; j++) bfr[j] = *(const bf16x8*)&Bl[swz(ncc + j * 16, slot)];
#pragma unroll
      for (int i = 0; i < 4; i++)
#pragma unroll
        for (int j = 0; j < 4; j++)
          acc[i][j] = __builtin_amdgcn_mfma_f32_16x16x32_bf16(af[i], bfr[j], acc[i][j], 0, 0, 0);
    }
  }
#undef STAGE
#undef UPDATE

  // epilogue: m = pix (A rows), n = co (B rows)
  int px0 = bp * 128 + wm * 64 + ((lane >> 4) << 2);
  int co0 = cot * 128 + wn * 64 + (lane & 15);
#pragma unroll
  for (int j = 0; j < 4; j++) {
    int co = co0 + j * 16;
    float bs = bias[co];
#pragma unroll
    for (int i = 0; i < 4; i++) {
#pragma unroll
      for (int r = 0; r < 4; r++) {
        float v = acc[i][j][r] + bs;
        int pix = px0 + i * 16 + r;
        if (OUT_TRANS_BF16)
          ((unsigned short*)outp)[((((size_t)b << 12) + pix) << 8) + co] = f2bf(v);
        else
          ((float*)outp)[((((size_t)b << 8) + co) << 12) + pix] = v;
      }
    }
  }
}

// ---------- fused instance norm + swish + xd 64->32 bilinear downsample ----------
__global__ __launch_bounds__(256) void k_post(float* __restrict__ x, float* __restrict__ xd) {
  __shared__ float sL[4096];
  __shared__ float s4[4];
  int bc = blockIdx.x;              // b*256 + ci
  float* p = x + (size_t)bc * NPIX;
  int tid = threadIdx.x;
  int lane = tid & 63, w = tid >> 6;
  float v[16];
  float s = 0.f;
#pragma unroll
  for (int i = 0; i < 16; i++) { v[i] = p[tid + i * 256]; s += v[i]; }
  s = wave_reduce_sum(s);
  if (lane == 0) s4[w] = s;
  __syncthreads();
  float mean = (s4[0] + s4[1] + s4[2] + s4[3]) * (1.0f / 4096.0f);
  __syncthreads();
  float s2 = 0.f;
#pragma unroll
  for (int i = 0; i < 16; i++) { float d = v[i] - mean; s2 += d * d; }
  s2 = wave_reduce_sum(s2);
  if (lane == 0) s4[w] = s2;
  __syncthreads();
  float var = (s4[0] + s4[1] + s4[2] + s4[3]) * (1.0f / 4096.0f);
  float inv = 1.0f / sqrtf(var + 1e-5f);
#pragma unroll
  for (int i = 0; i < 16; i++) {
    float xn = (v[i] - mean) * inv;
    float sg = 1.0f / (1.0f + expf(-xn));
    float o = xn * sg;
    p[tid + i * 256] = o;
    sL[tid + i * 256] = o;
  }
  __syncthreads();
  // xd: bilinear 64->32 align-corners, bit-same formula as k_resize
  float dyx = 63.0f / 31.0f;
  float* xdp = xd + (size_t)bc * NP;
#pragma unroll
  for (int k = 0; k < 4; k++) {
    int q = tid + k * 256;
    int yq = q >> 5, xq = q & 31;
    float yf = (float)yq * dyx;
    float xf = (float)xq * dyx;
    float y0f = floorf(yf), x0f = floorf(xf);
    int y0 = (int)y0f, x0 = (int)x0f;
    int y1 = min(y0 + 1, 63), x1 = min(x0 + 1, 63);
    float wy = yf - y0f, wx = xf - x0f;
    float a = sL[y0 * 64 + x0], b2 = sL[y0 * 64 + x1];
    float c2 = sL[y1 * 64 + x0], d2 = sL[y1 * 64 + x1];
    float top = a * (1.0f - wx) + b2 * wx;
    float bot = c2 * (1.0f - wx) + d2 * wx;
    xdp[q] = top * (1.0f - wy) + bot * wy;
  }
}

// ---------- xd f32 [b][ci][qpix] -> xdt bf16 [b][qpix][ci] (LDS tile transpose) ----------
__global__ __launch_bounds__(256) void k_trans_xd(const float* __restrict__ xd,
                                                  unsigned short* __restrict__ xdt) {
  __shared__ unsigned short T[64][66];
  int qt = blockIdx.x, ct = blockIdx.y, b = blockIdx.z;    // (16, 4, 8)
  int q0 = qt << 6, ci0 = ct << 6;
  int tid = threadIdx.x;
  {
    int r = tid >> 2, c4 = (tid & 3) << 4;
    const float* xb = xd + (((size_t)(b * 256 + ci0 + r)) << 10) + q0 + c4;
#pragma unroll
    for (int k = 0; k < 16; k += 4) {
      float4 f = *(const float4*)(xb + k);
      T[r][c4 + k + 0] = f2bf(f.x);
      T[r][c4 + k + 1] = f2bf(f.y);
      T[r][c4 + k + 2] = f2bf(f.z);
      T[r][c4 + k + 3] = f2bf(f.w);
    }
  }
  __syncthreads();
  {
    int qr = tid >> 2, cc = (tid & 3) << 4;
    unsigned int o[8];
#pragma unroll
    for (int k = 0; k < 8; k++) o[k] = pk2(T[cc + 2 * k][qr], T[cc + 2 * k + 1][qr]);
    size_t ob = ((((size_t)b << 10) + q0 + qr) << 8) + ci0 + cc;
    *(uint4*)&xdt[ob] = *(uint4*)&o[0];
    *(uint4*)&xdt[ob + 8] = *(uint4*)&o[4];
  }
}

// ---------- per-pixel channel sum of squares of x_down ----------
__global__ __launch_bounds__(256) void k_sq32(const float* __restrict__ xd, float* __restrict__ sq) {
  int idx = blockIdx.x * 256 + threadIdx.x;
  if (idx >= B_ * NP) return;
  int pix = idx & 1023; int b = idx >> 10;
  const float* p = xd + (size_t)b * C_ * NP + pix;
  float s = 0.f;
  for (int c = 0; c < C_; c++) { float v = p[c * NP]; s += v * v; }
  sq[idx] = s;
}

// ---------- fq[q] = mm ? 1/max(norm,1e-4) : 0  (mask32 bilinear computed inline) ----------
__global__ __launch_bounds__(256) void k_fq(const float* __restrict__ sq, const float* __restrict__ m64,
                                            float* __restrict__ fq) {
  int idx = blockIdx.x * 256 + threadIdx.x;
  if (idx >= B_ * NP) return;
  int q = idx & 1023, b = idx >> 10;
  int qi = q >> 5, qj = q & 31;
  const float* mb = m64 + (b << 12);
  float dyx = 63.0f / 31.0f;
  float ns = 0.f, ms = 0.f;
#pragma unroll
  for (int k = 0; k < 3; k++)
#pragma unroll
    for (int l = 0; l < 3; l++) {
      int r = qi + k - 1, c = qj + l - 1;
      if (r >= 0 && r < 32 && c >= 0 && c < 32) {
        ns += sq[b * NP + r * 32 + c];
        float yf = (float)r * dyx, xf = (float)c * dyx;
        float y0f = floorf(yf), x0f = floorf(xf);
        int y0 = (int)y0f, x0 = (int)x0f;
        int y1 = min(y0 + 1, 63), x1 = min(x0 + 1, 63);
        float wy = yf - y0f, wx = xf - x0f;
        float a = mb[y0 * 64 + x0], b2 = mb[y0 * 64 + x1];
        float c2 = mb[y1 * 64 + x0], d2 = mb[y1 * 64 + x1];
        float top = a * (1.0f - wx) + b2 * wx;
        float bot = c2 * (1.0f - wx) + d2 * wx;
        ms += top * (1.0f - wy) + bot * wy;
      }
    }
  float f = (ms == 0.0f) ? (1.0f / fmaxf(sqrtf(ns), 1e-4f)) : 0.0f;
  fq[idx] = f;
}

// ---------- Gram, 2-phase GLL16 pipeline BK=64, from xdt [b][qpix][ci] ----------
__global__ __launch_bounds__(256, 2) void k_gram2ph(const unsigned short* __restrict__ xdt,
                                                    const float* __restrict__ fq,
                                                    const unsigned short* __restrict__ zp,
                                                    float* __restrict__ sc) {
  __shared__ __align__(16) unsigned short AB[2][16384];
  int wgl = blockIdx.x + 8 * (blockIdx.y + 8 * blockIdx.z);      // grid (8,8,8)
  int nid = (wgl & 7) * 64 + (wgl >> 3);
  int bp = nid & 7, bq = (nid >> 3) & 7, b = nid >> 6;
  int tid = threadIdx.x, lane = tid & 63, w3 = tid >> 6;
  int wm = w3 >> 1, wn = w3 & 1;

  int rA = w3 * 32 + (lane >> 2), rA1 = rA + 16;
  int ds0 = (lane & 3) ^ (rA & 3) ^ ((rA >> 2) & 3);
  int ds1 = (lane & 3) ^ (rA1 & 3) ^ ((rA1 >> 2) & 3);
  int pA0r = bp * 128 + rA, pA1r = bp * 128 + rA1;
  int pB0r = bq * 128 + rA, pB1r = bq * 128 + rA1;
  int piA0 = pA0r >> 5, pjA0 = pA0r & 31, piA1 = pA1r >> 5, pjA1 = pA1r & 31;
  int piB0 = pB0r >> 5, pjB0 = pB0r & 31, piB1 = pB1r >> 5, pjB1 = pB1r & 31;
  const unsigned short* xb = xdt + (((size_t)b) << 18);

  f32x4 acc[4][4];
#pragma unroll
  for (int i = 0; i < 4; i++)
#pragma unroll
    for (int j = 0; j < 4; j++) acc[i][j] = (f32x4){0.f, 0.f, 0.f, 0.f};

  const unsigned short *pA0, *pA1, *pB0, *pB1;

#define GUPDATE(kkv) {                                                          \
    int kk_ = (kkv);                                                            \
    int dy_ = kk_ / 3 - 1, dx_ = kk_ % 3 - 1;                                   \
    int ya0 = piA0 + dy_, xa0 = pjA0 + dx_;                                     \
    int ya1 = piA1 + dy_, xa1 = pjA1 + dx_;                                     \
    int yb0 = piB0 + dy_, xb0 = pjB0 + dx_;                                     \
    int yb1 = piB1 + dy_, xb1 = pjB1 + dx_;                                     \
    pA0 = ((unsigned)ya0 < 32u && (unsigned)xa0 < 32u)                          \
        ? xb + ((((size_t)ya0 << 5) + xa0) << 8) + ds0 * 8 : zp + ds0 * 8;      \
    pA1 = ((unsigned)ya1 < 32u && (unsigned)xa1 < 32u)                          \
        ? xb + ((((size_t)ya1 << 5) + xa1) << 8) + ds1 * 8 : zp + ds1 * 8;      \
    pB0 = ((unsigned)yb0 < 32u && (unsigned)xb0 < 32u)                          \
        ? xb + ((((size_t)yb0 << 5) + xb0) << 8) + ds0 * 8 : zp + ds0 * 8;      \
    pB1 = ((unsigned)yb1 < 32u && (unsigned)xb1 < 32u)                          \
        ? xb + ((((size_t)yb1 << 5) + xb1) << 8) + ds1 * 8 : zp + ds1 * 8;      \
  }
#define GSTAGE(c2, buf) {                                                       \
    int ci0_ = ((c2) & 3) << 6;                                                 \
    unsigned short* lb_ = &AB[buf][0];                                          \
    GLL16(pA0 + ci0_,      lb_ + w3 * 1024);                                    \
    GLL16(pA1 + ci0_,      lb_ + w3 * 1024 + 512);                              \
    GLL16(pA0 + ci0_ + 32, lb_ + 4096 + w3 * 1024);                             \
    GLL16(pA1 + ci0_ + 32, lb_ + 4096 + w3 * 1024 + 512);                       \
    GLL16(pB0 + ci0_,      lb_ + 8192 + w3 * 1024);                             \
    GLL16(pB1 + ci0_,      lb_ + 8192 + w3 * 1024 + 512);                       \
    GLL16(pB0 + ci0_ + 32, lb_ + 12288 + w3 * 1024);                            \
    GLL16(pB1 + ci0_ + 32, lb_ + 12288 + w3 * 1024 + 512);                      \
  }

  GUPDATE(0);
  GSTAGE(0, 0);
  for (int c = 0; c < 36; ++c) {
    asm volatile("" ::: "memory");
    __builtin_amdgcn_s_barrier();
    asm volatile("" ::: "memory");
    if (c < 35) {
      int cn = c + 1;
      if ((cn & 3) == 0) GUPDATE(cn >> 2);
      GSTAGE(cn, cn & 1);
      asm volatile("s_waitcnt vmcnt(8)" ::: "memory");
    } else {
      asm volatile("s_waitcnt vmcnt(0)" ::: "memory");
    }
    __builtin_amdgcn_s_barrier();
    asm volatile("" ::: "memory");
    int slot = lane >> 4;
    int mr = wm * 64 + (lane & 15), ncc = wn * 64 + (lane & 15);
#pragma unroll
    for (int ks = 0; ks < 2; ++ks) {
      const unsigned short* Al = &AB[c & 1][ks << 12];
      const unsigned short* Bl = &AB[c & 1][8192 + (ks << 12)];
      bf16x8 af[4], bfr[4];
#pragma unroll
      for (int i = 0; i < 4; i++) af[i] = *(const bf16x8*)&Al[swz(mr + i * 16, slot)];
#pragma unroll
      for (int j = 0; j < 4; j++) bfr[j] = *(const bf16x8*)&Bl[swz(ncc + j * 16, slot)];
#pragma unroll
      for (int i = 0; i < 4; i++)
#pragma unroll
        for (int j = 0; j < 4; j++)
          acc[i][j] = __builtin_amdgcn_mfma_f32_16x16x32_bf16(af[i], bfr[j], acc[i][j], 0, 0, 0);
    }
  }
#undef GSTAGE
#undef GUPDATE

  int q0 = bq * 128 + wn * 64 + (lane & 15);
  int p0 = bp * 128 + wm * 64 + ((lane >> 4) << 2);
#pragma unroll
  for (int j = 0; j < 4; j++) {
    int q = q0 + j * 16;
    float f = fq[(b << 10) + q];
#pragma unroll
    for (int i = 0; i < 4; i++)
#pragma unroll
      for (int r = 0; r < 4; r++)
        sc[((size_t)(b << 10) + (p0 + i * 16 + r)) * NP + q] = acc[i][j][r] * f;
  }
}

// ---------- softmax over q for each (b,p); emits att in bf16 ----------
__global__ __launch_bounds__(256) void k_softmax(const float* __restrict__ sc, const float* __restrict__ fq,
                                                 unsigned short* __restrict__ attb) {
  __shared__ float s4[4];
  int row = blockIdx.x;        // b*1024 + p
  int b = row >> 10;
  const float* r = sc + (size_t)row * NP;
  int tid = threadIdx.x;
  int lane = tid & 63, w = tid >> 6;
  float4 sv = *(const float4*)&r[tid * 4];
  float l0 = sv.x * 10.f, l1 = sv.y * 10.f, l2 = sv.z * 10.f, l3 = sv.w * 10.f;
  float mx = fmaxf(fmaxf(l0, l1), fmaxf(l2, l3));
  mx = wave_reduce_max(mx);
  if (lane == 0) s4[w] = mx;
  __syncthreads();
  float M = fmaxf(fmaxf(s4[0], s4[1]), fmaxf(s4[2], s4[3]));
  __syncthreads();
  float e0 = expf(l0 - M), e1 = expf(l1 - M), e2 = expf(l2 - M), e3 = expf(l3 - M);
  float s = e0 + e1 + e2 + e3;
  s = wave_reduce_sum(s);
  if (lane == 0) s4[w] = s;
  __syncthreads();
  float inv = 1.0f / (s4[0] + s4[1] + s4[2] + s4[3]);
  const float* fb = fq + b * NP + tid * 4;
  float m0 = fb[0] > 0.f ? 1.f : 0.f;
  float m1 = fb[1] > 0.f ? 1.f : 0.f;
  float m2 = fb[2] > 0.f ? 1.f : 0.f;
  float m3 = fb[3] > 0.f ? 1.f : 0.f;
  float a0 = fmaxf(e0 * inv * m0, 1e-8f);
  float a1 = fmaxf(e1 * inv * m1, 1e-8f);
  float a2 = fmaxf(e2 * inv * m2, 1e-8f);
  float a3 = fmaxf(e3 * inv * m3, 1e-8f);
  uint2 o;
  o.x = pk2(f2bf(a0), f2bf(a1));
  o.y = pk2(f2bf(a2), f2bf(a3));
  *(uint2*)&attb[(size_t)row * NP + tid * 4] = o;
}

// ---------- x -> parity-split pre-shifted bf16 copies P0/P1/P2 ----------
__global__ __launch_bounds__(256) void k_xprep(const float* __restrict__ x,
                                               unsigned short* __restrict__ P0,
                                               unsigned short* __restrict__ P1,
                                               unsigned short* __restrict__ P2) {
  int idx = blockIdx.x * 256 + threadIdx.x;   // 2^20 total
  int xh8 = idx & 3;
  int yh = (idx >> 2) & 31;
  int co = (idx >> 7) & 255;
  int pc = (idx >> 15) & 3;
  int b  = idx >> 17;
  int cy = pc >> 1, cx = pc & 1;
  const float* row = x + ((size_t)(b * 256 + co) * 64 + (2 * yh + cy)) * 64 + 16 * xh8;
  float4 f0 = *(const float4*)(row);
  float4 f1 = *(const float4*)(row + 4);
  float4 f2 = *(const float4*)(row + 8);
  float4 f3 = *(const float4*)(row + 12);
  unsigned short v0 = f2bf(cx ? f0.y : f0.x), v1 = f2bf(cx ? f0.w : f0.z);
  unsigned short v2 = f2bf(cx ? f1.y : f1.x), v3 = f2bf(cx ? f1.w : f1.z);
  unsigned short v4 = f2bf(cx ? f2.y : f2.x), v5 = f2bf(cx ? f2.w : f2.z);
  unsigned short v6 = f2bf(cx ? f3.y : f3.x), v7 = f2bf(cx ? f3.w : f3.z);
  int prev = __shfl_up((int)v7, 1, 64);
  int next = __shfl_down((int)v0, 1, 64);
  unsigned short pv = (xh8 == 0) ? (unsigned short)0 : (unsigned short)prev;
  unsigned short nx = (xh8 == 3) ? (unsigned short)0 : (unsigned short)next;
  size_t base = ((size_t)((b * 4 + pc) * 256 + co) * 32 + yh) * 32 + 8 * xh8;
  uint4 w0 = {pk2(v0, v1), pk2(v2, v3), pk2(v4, v5), pk2(v6, v7)};
  *(uint4*)&P0[base] = w0;
  uint4 w1 = {pk2(pv, v0), pk2(v1, v2), pk2(v3, v4), pk2(v5, v6)};
  *(uint4*)&P1[base] = w1;
  uint4 w2 = {pk2(v1, v2), pk2(v3, v4), pk2(v5, v6), pk2(v7, nx)};
  *(uint4*)&P2[base] = w2;
}

// ---------- PV class-GEMM, 2-phase counted-vmcnt pipeline BK=64 ----------
__global__ __launch_bounds__(256, 2) void k_pv(const unsigned short* __restrict__ attb,
                                               const unsigned short* __restrict__ P0,
                                               const unsigned short* __restrict__ P1,
                                               const unsigned short* __restrict__ P2,
                                               const unsigned short* __restrict__ zp,
                                               const float* __restrict__ xbuf,
                                               const float* __restrict__ m64,
                                               float* __restrict__ out) {
  __shared__ __align__(16) unsigned short AB[2][16384];
  int wg = blockIdx.x + blockIdx.y * 8 + blockIdx.z * 16;
  int nid = (wg & 7) * 64 + (wg >> 3);
  int bn = nid & 7, bm = (nid >> 3) & 1, z = nid >> 4;
  int b = z >> 2, cls = z & 3, cy = cls >> 1, cx = cls & 1;
  int tid = threadIdx.x, lane = tid & 63, w3 = tid >> 6;
  int wm = w3 >> 1, wn = w3 & 1;

  int dy1 = cy ? -1 : 1;
  int pio1 = cy ? 1 : -1;
  int pjo1 = cx ? 1 : -1;
  const unsigned short* Pdx = cx ? P1 : P2;

  int rA0 = w3 * 32 + (lane >> 2);
  int rA1 = rA0 + 16;
  int ds0 = (lane & 3) ^ (rA0 & 3) ^ ((rA0 >> 2) & 3);
  int ds1 = (lane & 3) ^ (rA1 & 3) ^ ((rA1 >> 2) & 3);
  int offA0 = ((z * 256 + bm * 128 + rA0) << 10) + ds0 * 8;
  int offA1 = ((z * 256 + bm * 128 + rA1) << 10) + ds1 * 8;

  const unsigned short* attB = attb + ((size_t)b << 20);
  int o0 = bn * 128 + rA0, o1 = bn * 128 + rA1;
  int oy0 = o0 >> 5, ox0 = o0 & 31, oy1 = o1 >> 5, ox1 = o1 & 31;
#define BPTR(oyv, oxv, dsv, tyv, txv) ({                                        \
    int pi = (oyv) + ((tyv) ? pio1 : 0);                                        \
    int pj = (oxv) + ((txv) ? pjo1 : 0);                                        \
    (pi >= 0 && pi < 32 && pj >= 0 && pj < 32)                                  \
        ? attB + (((pi << 5) + pj) << 10) + (dsv) * 8 : zp; })
  const unsigned short* b0t0 = BPTR(oy0, ox0, ds0, 0, 0);
  const unsigned short* b0t1 = BPTR(oy0, ox0, ds0, 0, 1);
  const unsigned short* b0t2 = BPTR(oy0, ox0, ds0, 1, 0);
  const unsigned short* b0t3 = BPTR(oy0, ox0, ds0, 1, 1);
  const unsigned short* b1t0 = BPTR(oy1, ox1, ds1, 0, 0);
  const unsigned short* b1t1 = BPTR(oy1, ox1, ds1, 0, 1);
  const unsigned short* b1t2 = BPTR(oy1, ox1, ds1, 1, 0);
  const unsigned short* b1t3 = BPTR(oy1, ox1, ds1, 1, 1);
#undef BPTR

  f32x4 acc[4][4];
#pragma unroll
  for (int i = 0; i < 4; i++)
#pragma unroll
    for (int j = 0; j < 4; j++) acc[i][j] = (f32x4){0.f, 0.f, 0.f, 0.f};

  int dA0 = w3 * 1024, dA1 = w3 * 1024 + 512;
  int dB0 = 8192 + w3 * 1024, dB1 = 8192 + w3 * 1024 + 512;

#define PHALF(o2, buf, h) {                                                     \
    int t2 = (o2) >> 5, qi = (o2) & 31;                                         \
    int q32 = qi * 32;                                                          \
    const unsigned short* Ab = (t2 & 1) ? Pdx : P0;                             \
    int dyo = (t2 >> 1) ? dy1 * 32 : 0;                                         \
    bool vA = (t2 < 2) || ((dy1 > 0) ? (qi < 31) : (qi > 0));                   \
    if (!vA) Ab = zp;                                                           \
    int oA0 = vA ? offA0 + dyo + q32 : 0;                                       \
    int oA1 = vA ? offA1 + dyo + q32 : 0;                                       \
    unsigned short* lb = &AB[buf][(h) << 12];                                   \
    GLL16(Ab + oA0, lb + dA0);                                                  \
    GLL16(Ab + oA1, lb + dA1);                                                  \
    const unsigned short* sB0 = (t2 == 0 ? b0t0 : t2 == 1 ? b0t1 : t2 == 2 ? b0t2 : b0t3) + q32; \
    const unsigned short* sB1 = (t2 == 0 ? b1t0 : t2 == 1 ? b1t1 : t2 == 2 ? b1t2 : b1t3) + q32; \
    GLL16(sB0, lb + dB0);                                                       \
    GLL16(sB1, lb + dB1);                                                       \
  }
#define PSTAGE(c2, buf) { PHALF(2 * (c2), buf, 0); PHALF(2 * (c2) + 1, buf, 1); }

  PSTAGE(0, 0);
  for (int c = 0; c < 64; ++c) {
    asm volatile("" ::: "memory");
    __builtin_amdgcn_s_barrier();
    asm volatile("" ::: "memory");
    if (c < 63) {
      PSTAGE(c + 1, (c + 1) & 1);
      asm volatile("s_waitcnt vmcnt(8)" ::: "memory");
    } else {
      asm volatile("s_waitcnt vmcnt(0)" ::: "memory");
    }
    __builtin_amdgcn_s_barrier();
    asm volatile("" ::: "memory");
    int slot = lane >> 4;
    int mr = wm * 64 + (lane & 15), ncc = wn * 64 + (lane & 15);
#pragma unroll
    for (int ks = 0; ks < 2; ++ks) {
      const unsigned short* Al = &AB[c & 1][ks << 12];
      const unsigned short* Bl = &AB[c & 1][8192 + (ks << 12)];
      bf16x8 af[4], bfr[4];
#pragma unroll
      for (int i = 0; i < 4; i++) af[i] = *(const bf16x8*)&Al[swz(mr + i * 16, slot)];
#pragma unroll
      for (int j = 0; j < 4; j++) bfr[j] = *(const bf16x8*)&Bl[swz(ncc + j * 16, slot)];
#pragma unroll
      for (int i = 0; i < 4; i++)
#pragma unroll
        for (int j = 0; j < 4; j++)
          acc[i][j] = __builtin_amdgcn_mfma_f32_16x16x32_bf16(af[i], bfr[j], acc[i][j], 0, 0, 0);
    }
  }
#undef PSTAGE
#undef PHALF

  int co0 = bm * 128 + wm * 64 + ((lane >> 4) << 2);
  int oo0 = bn * 128 + wn * 64 + (lane & 15);
#pragma unroll
  for (int j = 0; j < 4; j++) {
    int o = oo0 + j * 16;
    int oy = ((o >> 5) << 1) + cy, ox = ((o & 31) << 1) + cx;
    int opix = oy * 64 + ox;
    float msk = m64[b * NPIX + opix];
    float s = 0.25f * msk, t1m = 1.0f - msk;
#pragma unroll
    for (int i = 0; i < 4; i++) {
#pragma unroll
      for (int r = 0; r < 4; r++) {
        int co = co0 + i * 16 + r;
        size_t xi = (size_t)(b * C_ + co) * NPIX + opix;
        out[xi] = acc[i][j][r] * s + xbuf[xi] * t1m;
      }
    }
  }
}

extern "C" void kernel_launch(void* const* d_in, const int* in_sizes, int n_in,
                              void* d_out, int out_size, void* d_ws, size_t ws_size,
                              hipStream_t stream) {
  const float* bg   = (const float*)d_in[0];
  const float* fg   = (const float*)d_in[1];
  const float* mask = (const float*)d_in[2];
  const float* Wc   = (const float*)d_in[3];
  const float* bc   = (const float*)d_in[4];
  const float* Wm   = (const float*)d_in[5];
  const float* bm   = (const float*)d_in[6];
  const float* Wf   = (const float*)d_in[7];
  const float* bf   = (const float*)d_in[8];
  float* out = (float*)d_out;
  float* w = (float*)d_ws;

  // workspace (float offsets), total 25,231,360 floats = 100.9 MB
  float* mask64 = w;                          // 32768
  float* sq32   = w + 40960;                  // 8192
  float* fq     = w + 49152;                  // 8192
  float* bias1  = w + 57344;                  // 256
  float* zpage  = w + 57600;                  // 2048 zeros (8 KB)
  // region1 [65536, 8454144): A0t/A1t (convs) -> sc f32 (gram/softmax) -> P0+P1 (pv)
  unsigned short* A0t = (unsigned short*)(w + 65536);            // [b][pix][ci]
  unsigned short* A1t = (unsigned short*)(w + 65536 + 4194304);
  float* sc = w + 65536;
  unsigned short* P0u = (unsigned short*)(w + 65536);
  unsigned short* P1u = (unsigned short*)(w + 4259840);
  // region2 [8454144, 12648448): tbuf_t bf16 -> xd f32 + xdt bf16 -> attb bf16
  unsigned short* tbuf_t = (unsigned short*)(w + 8454144);       // [b][pix][co]
  float* xd = w + 8454144;                    // 2097152 floats [b][ci][qpix]
  unsigned short* xdt = (unsigned short*)(w + 10551296);         // [b][qpix][ci]
  unsigned short* attb = (unsigned short*)(w + 8454144);
  float* xbuf = w + 12648448;                 // 8388608 [b][co][pix]
  unsigned short* Wp1 = (unsigned short*)(w + 21037056);
  unsigned short* Wp2 = (unsigned short*)(w + 21626880);
  unsigned short* P2u = (unsigned short*)(w + 21037056);         // after convs

  const unsigned short* zp = (const unsigned short*)zpage;

  hipLaunchKernelGGL(k_resize, dim3(128), dim3(256), 0, stream, mask, mask64, 256, 256, 64, 64, 32768);
  hipLaunchKernelGGL(k_wprep, dim3(6912), dim3(256), 0, stream, Wc, Wm, Wf, Wp1, Wp2);
  hipLaunchKernelGGL(k_bias, dim3(1), dim3(256), 0, stream, bc, bm, bias1, zpage);
  hipLaunchKernelGGL(k_prepAT, dim3(64, 4, 8), dim3(256), 0, stream, fg, bg, mask64, A0t, A1t);
  // conv1 (dual masked conv, K=4608) -> tbuf_t bf16 [pix][co]
  hipLaunchKernelGGL((k_conv2ph<18, true>), dim3(32, 2, 8), dim3(256), 0, stream,
                     A0t, A1t, Wp1, bias1, zp, (void*)tbuf_t);
  // conv2 (K=2304) -> xbuf f32 [co][pix]
  hipLaunchKernelGGL((k_conv2ph<9, false>), dim3(32, 2, 8), dim3(256), 0, stream,
                     tbuf_t, tbuf_t, Wp2, bf, zp, (void*)xbuf);
  // fused instance-norm + swish + xd downsample
  hipLaunchKernelGGL(k_post, dim3(B_ * C_), dim3(256), 0, stream, xbuf, xd);
  hipLaunchKernelGGL(k_trans_xd, dim3(16, 4, 8), dim3(256), 0, stream, xd, xdt);
  hipLaunchKernelGGL(k_sq32, dim3(32), dim3(256), 0, stream, xd, sq32);
  hipLaunchKernelGGL(k_fq, dim3(32), dim3(256), 0, stream, sq32, mask64, fq);
  hipLaunchKernelGGL(k_gram2ph, dim3(8, 8, 8), dim3(256), 0, stream, xdt, fq, zp, sc);
  hipLaunchKernelGGL(k_softmax, dim3(B_ * NP), dim3(256), 0, stream, sc, fq, attb);
  hipLaunchKernelGGL(k_xprep, dim3(4096), dim3(256), 0, stream, xbuf, P0u, P1u, P2u);
  hipLaunchKernelGGL(k_pv, dim3(8, 2, 32), dim3(256), 0, stream, attb, P0u, P1u, P2u,
                     zp, xbuf, mask64, out);
}